// Round 5
// baseline (159.749 us; speedup 1.0000x reference)
//
#include <hip/hip_runtime.h>

typedef unsigned short u16;
typedef float f32x4 __attribute__((ext_vector_type(4)));
typedef float f32x16 __attribute__((ext_vector_type(16)));
typedef __bf16 bfx8 __attribute__((ext_vector_type(8)));
typedef __bf16 bfx4 __attribute__((ext_vector_type(4)));
typedef __bf16 bfx2 __attribute__((ext_vector_type(2)));
typedef u16 u16x8 __attribute__((ext_vector_type(8)));
typedef u16 u16x4 __attribute__((ext_vector_type(4)));
typedef unsigned u32x2 __attribute__((ext_vector_type(2)));
typedef unsigned u32x4 __attribute__((ext_vector_type(4)));

#define B_ 2
#define S_ 2048
#define E_ 1024
#define H_ 16
#define D_ 64

__device__ __forceinline__ u16 f2bf(float f) {
  unsigned u = __float_as_uint(f);
  u = u + 0x7FFFu + ((u >> 16) & 1u);  // RNE
  return (u16)(u >> 16);
}

// XOR swizzle for tiles with 128B rows: byte ^= ((row&7)<<4).
__device__ __forceinline__ int swz128(int o) { return o ^ ((o >> 3) & 0x70); }

// async global->LDS, 16B per lane; LDS dest is wave-uniform base (HW adds lane*16).
__device__ __forceinline__ void gload16(const void* g, void* l) {
  __builtin_amdgcn_global_load_lds((const __attribute__((address_space(1))) void*)g,
                                   (__attribute__((address_space(3))) void*)l, 16, 0, 0);
}

// ---------------- fp32 -> bf16 convert (vectorized) ----------------
__global__ void cvt_f32_bf16(const float* __restrict__ in, u16* __restrict__ out, int n4) {
  int stride = gridDim.x * blockDim.x;
  for (int i = blockIdx.x * blockDim.x + threadIdx.x; i < n4; i += stride) {
    const float4 v = reinterpret_cast<const float4*>(in)[i];
    u16x4 o = {f2bf(v.x), f2bf(v.y), f2bf(v.z), f2bf(v.w)};
    reinterpret_cast<u16x4*>(out)[i] = o;
  }
}

// ---------------- transpose + convert: out[C][R] (bf16) = in[R][C] (f32) ----------------
__global__ __launch_bounds__(256) void tcvt(const float* __restrict__ in, u16* __restrict__ out,
                                            int R, int C) {
  __shared__ float tile[64][65];
  const int ct = blockIdx.x * 64, rt = blockIdx.y * 64;
  const int tid = threadIdx.x;
#pragma unroll
  for (int p = 0; p < 4; ++p) {
    int f = p * 256 + tid;
    int row = f >> 4, c4 = (f & 15) << 2;
    const float4 v = *reinterpret_cast<const float4*>(in + (size_t)(rt + row) * C + ct + c4);
    tile[row][c4 + 0] = v.x; tile[row][c4 + 1] = v.y;
    tile[row][c4 + 2] = v.z; tile[row][c4 + 3] = v.w;
  }
  __syncthreads();
#pragma unroll
  for (int p = 0; p < 4; ++p) {
    int g = p * 256 + tid;
    int orow = g >> 4, k4 = (g & 15) << 2;
    u16x4 o = {f2bf(tile[k4 + 0][orow]), f2bf(tile[k4 + 1][orow]),
               f2bf(tile[k4 + 2][orow]), f2bf(tile[k4 + 3][orow])};
    *reinterpret_cast<u16x4*>(out + (size_t)(ct + orow) * R + rt + k4) = o;
  }
}

// ---------------- V transpose per (b,h): [S][D] -> [D][S] (bf16) ----------------
__global__ __launch_bounds__(256) void vtrans(const u16* __restrict__ V, u16* __restrict__ Vt) {
  __shared__ u16 tile[64][72];
  const int st = blockIdx.x * 64;
  const int bh = blockIdx.y;
  const int tid = threadIdx.x;
  const u16* src = V + ((size_t)bh * S_ + st) * D_;
#pragma unroll
  for (int p = 0; p < 2; ++p) {
    int g = p * 256 + tid;
    int row = g >> 3, c8 = (g & 7) << 3;
    u16x8 v = *reinterpret_cast<const u16x8*>(src + row * D_ + c8);
#pragma unroll
    for (int j = 0; j < 8; ++j) tile[row][c8 + j] = v[j];
  }
  __syncthreads();
  u16* dst = Vt + (size_t)bh * D_ * S_ + st;
#pragma unroll
  for (int p = 0; p < 2; ++p) {
    int g = p * 256 + tid;
    int d = g >> 3, s8 = (g & 7) << 3;
    u16x8 o;
#pragma unroll
    for (int j = 0; j < 8; ++j) o[j] = tile[s8 + j][d];
    *reinterpret_cast<u16x8*>(dst + (size_t)d * S_ + s8) = o;
  }
}

// ---------------- bf16 GEMM: C[M][N] = A[M][K] @ Bt[N][K]^T (+bias) ----------------
// Staging via global_load_lds w=16; linear LDS dest, pre-swizzled source; readers swz128.
// XCD-chunked block swizzle (T1) for L2 locality.
template <int EPI>
__global__ __launch_bounds__(256) void gemm_bt(const u16* __restrict__ A,
                                               const u16* __restrict__ Bt,
                                               const float* __restrict__ bias, int M, int N, int K,
                                               float* __restrict__ outF, u16* __restrict__ outK,
                                               u16* __restrict__ outQ, u16* __restrict__ outV) {
  __shared__ __align__(16) u16 sA[128 * 64];
  __shared__ __align__(16) u16 sB[128 * 64];
  const int tid = threadIdx.x, lane = tid & 63;
  const int wave = tid >> 6, wr = wave >> 1, wc = wave & 1;
  int lin = blockIdx.y * gridDim.x + blockIdx.x;
  const int nwg = gridDim.x * gridDim.y;
  if ((nwg & 7) == 0) {  // bijective XCD-chunked swizzle
    const int cpx = nwg >> 3;
    lin = (lin & 7) * cpx + (lin >> 3);
  }
  const int bm = (lin / gridDim.x) * 128, bn = (lin % gridDim.x) * 128;
  const int r8 = lane >> 3, c16 = (lane & 7) ^ r8;
  f32x4 acc[4][4] = {};
  for (int k0 = 0; k0 < K; k0 += 64) {
#pragma unroll
    for (int i = 0; i < 4; ++i) {
      const int c = wave * 4 + i;
      const int row = c * 8 + r8;
      gload16(A + (size_t)(bm + row) * K + k0 + c16 * 8, (char*)sA + c * 1024);
      gload16(Bt + (size_t)(bn + row) * K + k0 + c16 * 8, (char*)sB + c * 1024);
    }
    __syncthreads();  // vmcnt(0) drain: tile ready
#pragma unroll
    for (int kc = 0; kc < 2; ++kc) {
      bfx8 af[4], bf[4];
#pragma unroll
      for (int mf = 0; mf < 4; ++mf) {
        int o = swz128(((wr * 64 + mf * 16 + (lane & 15)) << 7) + kc * 64 + ((lane >> 4) << 4));
        af[mf] = *reinterpret_cast<const bfx8*>(reinterpret_cast<const char*>(sA) + o);
      }
#pragma unroll
      for (int nf = 0; nf < 4; ++nf) {
        int o = swz128(((wc * 64 + nf * 16 + (lane & 15)) << 7) + kc * 64 + ((lane >> 4) << 4));
        bf[nf] = *reinterpret_cast<const bfx8*>(reinterpret_cast<const char*>(sB) + o);
      }
#pragma unroll
      for (int mf = 0; mf < 4; ++mf)
#pragma unroll
        for (int nf = 0; nf < 4; ++nf)
          acc[mf][nf] = __builtin_amdgcn_mfma_f32_16x16x32_bf16(af[mf], bf[nf], acc[mf][nf], 0, 0, 0);
    }
    __syncthreads();  // protect LDS before next stage
  }
#pragma unroll
  for (int mf = 0; mf < 4; ++mf)
#pragma unroll
    for (int nf = 0; nf < 4; ++nf)
#pragma unroll
      for (int r = 0; r < 4; ++r) {
        const int row = bm + wr * 64 + mf * 16 + ((lane >> 4) << 2) + r;
        const int col = bn + wc * 64 + nf * 16 + (lane & 15);
        const float v = acc[mf][nf][r] + bias[col];
        if (EPI == 1) {
          outF[(size_t)row * N + col] = v;
        } else {
          const int chunk = col >> 10, w = col & 1023, h = w >> 6, dd = w & 63;
          const int b = row >> 11, s = row & 2047;
          const size_t idx = (((size_t)(b * H_ + h)) * S_ + s) * D_ + dd;
          u16* dst = (chunk == 0) ? outK : (chunk == 1) ? outQ : outV;
          dst[idx] = f2bf(v);
        }
      }
}

// ---------------- flash attention with ALiBi, causal (32x32 MFMA, in-register P) ----------------
// QBLK=128, 4 waves, wave owns 32 q rows. tt = mfma_32x32x16(K, Q): lane holds col=q=lane&31,
// 16 keys in regs at crow=(reg&3)+8*(reg>>2)+4*hf (partner lane^32 holds the other 16).
// Softmax lane-local in exp2 domain; ALiBi row-term (-slope*i) cancels in softmax.
// P repack for PV fully in-register via permlane32_swap: swap(w[j], w[j+2]) -> {word_j, word_{j+2}}
// (vdst-upper <-> src-lower semantics, per verified m214v22 recipe). No LDS P bounce.
__global__ __launch_bounds__(256) void attn_alibi(const u16* __restrict__ Q,
                                                  const u16* __restrict__ Kb,
                                                  const u16* __restrict__ Vt,
                                                  const float* __restrict__ slopes,
                                                  u16* __restrict__ Y) {
  __shared__ __align__(16) u16 sK[2][4096];
  __shared__ __align__(16) u16 sV[2][4096];
  const int id = blockIdx.x;
  const int hi2 = id >> 8, rem = id & 255;
  const int qi = hi2 ? (rem & 15) : (15 - (rem & 15));  // balanced: CU pair gets qi & 15-qi
  const int bh = (rem >> 4) + (hi2 << 4);
  const int b = bh >> 4, h = bh & 15;
  const int tid = threadIdx.x, lane = tid & 63, wave = tid >> 6;
  const int q = lane & 31, hf = lane >> 5;
  const int q0 = qi * 128;
  const int w0 = q0 + wave * 32;  // wave's first q row
  const float L2E = 1.44269504089f;
  const float SCALE = 0.125f * L2E;
  const float sl2 = slopes[h] * L2E;
  const size_t headSD = (size_t)bh * (S_ * D_);
  const size_t headDS = (size_t)bh * (D_ * S_);
  const int nt = 2 * qi + 2;
  const int r8 = lane >> 3, c16 = (lane & 7) ^ r8;

  // Q fragments (B-operand): lane holds q row, d = kc*16 + hf*8 + e
  bfx8 qf[4];
  {
    const u16* qp = Q + headSD + (size_t)(w0 + q) * D_ + hf * 8;
#pragma unroll
    for (int kc = 0; kc < 4; ++kc) qf[kc] = *reinterpret_cast<const bfx8*>(qp + kc * 16);
  }
  // per-reg key bias base (log2 domain): key-in-block crow(reg) = (reg&3)+8*(reg>>2)+4*hf
  f32x16 base;
#pragma unroll
  for (int reg = 0; reg < 16; ++reg)
    base[reg] = sl2 * (float)((reg & 3) + 8 * (reg >> 2) + 4 * hf);

  float m = 0.f, l = 0.f;
  f32x16 oT[2] = {};  // rows = d (16 per db), col = q

  auto stage = [&](int t, int buf) {
#pragma unroll
    for (int i = 0; i < 2; ++i) {
      const int c = wave * 2 + i;  // chunk 0..7 of 8KB tile
      const int row = c * 8 + r8;  // K: key row; V: d row
      gload16(Kb + headSD + (size_t)t * 4096 + row * 64 + c16 * 8, (char*)sK[buf] + c * 1024);
      gload16(Vt + headDS + (size_t)row * S_ + t * 64 + c16 * 8, (char*)sV[buf] + c * 1024);
    }
  };

  stage(0, 0);
  __syncthreads();
  int cur = 0;
  for (int t = 0; t < nt; ++t) {
    if (t + 1 < nt) stage(t + 1, cur ^ 1);  // in flight across compute; drained at barrier
    const bool act0 = (t * 64 <= w0 + 31);
    const bool act1 = (t * 64 + 32 <= w0 + 31);
    if (act0) {
      const char* sKc = reinterpret_cast<const char*>(sK[cur]);
      const char* sVc = reinterpret_cast<const char*>(sV[cur]);
      f32x16 tt0 = {}, tt1 = {};
#pragma unroll
      for (int kc = 0; kc < 4; ++kc) {
        const bfx8 kf = *reinterpret_cast<const bfx8*>(sKc + swz128((q << 7) + kc * 32 + hf * 16));
        tt0 = __builtin_amdgcn_mfma_f32_32x32x16_bf16(kf, qf[kc], tt0, 0, 0, 0);
      }
      if (act1) {
#pragma unroll
        for (int kc = 0; kc < 4; ++kc) {
          const bfx8 kf =
              *reinterpret_cast<const bfx8*>(sKc + swz128(((32 + q) << 7) + kc * 32 + hf * 16));
          tt1 = __builtin_amdgcn_mfma_f32_32x32x16_bf16(kf, qf[kc], tt1, 0, 0, 0);
        }
      }
      // bias + causal mask + running-max (all relative to current m)
      const float tb0 = sl2 * (float)(t * 64) - m;
      const float tb1 = tb0 + sl2 * 32.f;
      const int ir0 = w0 + q - t * 64;  // mask: crow(reg) > ir0
      const bool mask0 = (t * 64 + 31 > w0);
      const bool mask1 = (t * 64 + 63 > w0);
      float rmax = -3.0e38f;
#pragma unroll
      for (int reg = 0; reg < 16; ++reg) {
        float sv = fmaf(tt0[reg], SCALE, tb0 + base[reg]);
        if (mask0) {
          const int rv = (reg & 3) + 8 * (reg >> 2) + 4 * hf;
          sv = (rv > ir0) ? -3.0e38f : sv;
        }
        tt0[reg] = sv;
        rmax = fmaxf(rmax, sv);
      }
      if (act1) {
#pragma unroll
        for (int reg = 0; reg < 16; ++reg) {
          float sv = fmaf(tt1[reg], SCALE, tb1 + base[reg]);
          if (mask1) {
            const int rv = (reg & 3) + 8 * (reg >> 2) + 4 * hf;
            sv = (rv > ir0 - 32) ? -3.0e38f : sv;
          }
          tt1[reg] = sv;
          rmax = fmaxf(rmax, sv);
        }
      }
      rmax = fmaxf(rmax, __shfl_xor(rmax, 32));  // cross-half: full row max over this tile
      if (!__all(rmax <= 12.0f)) {  // defer-max (T13), log2 domain
        const float up = fmaxf(rmax, 0.f);
        const float corr = __builtin_amdgcn_exp2f(-up);
        m += up;
        l *= corr;
        oT[0] *= corr;
        oT[1] *= corr;
        tt0 -= up;
        if (act1) tt1 -= up;
      }
      // exp2 + row-sum + pack to bf16 words (pairs of consecutive keys)
      float rsum = 0.f;
      unsigned pw0[8], pw1[8];
#pragma unroll
      for (int j = 0; j < 8; ++j) {
        const float e0 = __builtin_amdgcn_exp2f(tt0[2 * j]);
        const float e1 = __builtin_amdgcn_exp2f(tt0[2 * j + 1]);
        rsum += e0 + e1;
        bfx2 p = {(__bf16)e0, (__bf16)e1};
        pw0[j] = __builtin_bit_cast(unsigned, p);
      }
      if (act1) {
#pragma unroll
        for (int j = 0; j < 8; ++j) {
          const float e0 = __builtin_amdgcn_exp2f(tt1[2 * j]);
          const float e1 = __builtin_amdgcn_exp2f(tt1[2 * j + 1]);
          rsum += e0 + e1;
          bfx2 p = {(__bf16)e0, (__bf16)e1};
          pw1[j] = __builtin_bit_cast(unsigned, p);
        }
      }
      rsum += __shfl_xor(rsum, 32);
      l += rsum;
      // PV: oT[db] += V^T-frag x P^T-frag. In-register P redistribution:
      // swap(pw[j], pw[j+2]): r[0] = frag word j, r[1] = frag word j+2
      // (vdst'[32:63] = src[0:31]; src'[0:31] = vdst[32:63]).
#pragma unroll
      for (int kb = 0; kb < 2; ++kb) {
        if (kb == 1 && !act1) break;
        const unsigned* pw = (kb == 0) ? pw0 : pw1;
#pragma unroll
        for (int kk = 0; kk < 2; ++kk) {
          const u32x2 ra =
              __builtin_amdgcn_permlane32_swap(pw[4 * kk + 0], pw[4 * kk + 2], false, false);
          const u32x2 rb =
              __builtin_amdgcn_permlane32_swap(pw[4 * kk + 1], pw[4 * kk + 3], false, false);
          const u32x4 fw = {ra[0], rb[0], ra[1], rb[1]};
          const bfx8 pf = __builtin_bit_cast(bfx8, fw);
          const int kchunk = kb * 2 + kk;
#pragma unroll
          for (int db = 0; db < 2; ++db) {
            const bfx8 vf = *reinterpret_cast<const bfx8*>(
                sVc + swz128(((db * 32 + q) << 7) + kchunk * 32 + hf * 16));
            oT[db] = __builtin_amdgcn_mfma_f32_32x32x16_bf16(vf, pf, oT[db], 0, 0, 0);
          }
        }
      }
    }
    __syncthreads();  // drains prefetch vmcnt; protects sK/sV swap
    cur ^= 1;
  }
  const float rl = 1.0f / l;
  const int row = w0 + q;
#pragma unroll
  for (int db = 0; db < 2; ++db)
#pragma unroll
    for (int grp = 0; grp < 4; ++grp) {
      bfx4 w = {(__bf16)(oT[db][grp * 4 + 0] * rl), (__bf16)(oT[db][grp * 4 + 1] * rl),
                (__bf16)(oT[db][grp * 4 + 2] * rl), (__bf16)(oT[db][grp * 4 + 3] * rl)};
      const int col = h * 64 + db * 32 + 8 * grp + 4 * hf;
      *reinterpret_cast<bfx4*>(reinterpret_cast<char*>(Y) +
                               (((size_t)b * S_ + row) * E_ + col) * 2) = w;
    }
}

extern "C" void kernel_launch(void* const* d_in, const int* in_sizes, int n_in, void* d_out,
                              int out_size, void* d_ws, size_t ws_size, hipStream_t stream) {
  (void)in_sizes; (void)n_in; (void)out_size; (void)ws_size;
  const float* x = (const float*)d_in[0];
  const float* Wkqv = (const float*)d_in[1];
  const float* bkqv = (const float*)d_in[2];
  const float* Wproj = (const float*)d_in[3];
  const float* bproj = (const float*)d_in[4];
  const float* slopes = (const float*)d_in[5];
  float* out = (float*)d_out;

  const size_t MBE = (size_t)4096 * 1024;
  u16* xb = (u16*)d_ws;                       // x in bf16           [4096][1024]
  u16* wkqvt = xb + MBE;                      // W_kqv^T bf16        [3072][1024]
  u16* wprojt = wkqvt + (size_t)3072 * 1024;  // W_proj^T bf16       [1024][1024]
  u16* kbuf = wprojt + (size_t)1024 * 1024;   // K  [B][H][S][D]
  u16* qbuf = kbuf + MBE;                     // Q  [B][H][S][D]
  u16* vbuf = qbuf + MBE;                     // V  [B][H][S][D]
  u16* vtbuf = vbuf + MBE;                    // V^T [B][H][D][S]
  u16* ybuf = vtbuf + MBE;                    // attn out [B][S][E]

  cvt_f32_bf16<<<dim3(2048), dim3(256), 0, stream>>>(x, xb, (int)(MBE / 4));
  tcvt<<<dim3(48, 16), dim3(256), 0, stream>>>(Wkqv, wkqvt, 1024, 3072);
  tcvt<<<dim3(16, 16), dim3(256), 0, stream>>>(Wproj, wprojt, 1024, 1024);
  gemm_bt<0><<<dim3(24, 32), dim3(256), 0, stream>>>(xb, wkqvt, bkqv, 4096, 3072, 1024,
                                                     (float*)nullptr, kbuf, qbuf, vbuf);
  vtrans<<<dim3(32, 32), dim3(256), 0, stream>>>(vbuf, vtbuf);
  attn_alibi<<<dim3(512), dim3(256), 0, stream>>>(qbuf, kbuf, vtbuf, slopes, ybuf);
  gemm_bt<1><<<dim3(8, 32), dim3(256), 0, stream>>>(ybuf, wprojt, bproj, 4096, 1024, 1024, out,
                                                    nullptr, nullptr, nullptr);
}

// Round 6
// 122.489 us; speedup vs baseline: 1.3042x; 1.3042x over previous
//
#include <hip/hip_runtime.h>

typedef unsigned short u16;
typedef float f32x4 __attribute__((ext_vector_type(4)));
typedef __bf16 bfx8 __attribute__((ext_vector_type(8)));
typedef __bf16 bfx4 __attribute__((ext_vector_type(4)));
typedef u16 u16x8 __attribute__((ext_vector_type(8)));
typedef u16 u16x4 __attribute__((ext_vector_type(4)));

#define B_ 2
#define S_ 2048
#define E_ 1024
#define H_ 16
#define D_ 64

__device__ __forceinline__ u16 f2bf(float f) {
  unsigned u = __float_as_uint(f);
  u = u + 0x7FFFu + ((u >> 16) & 1u);  // RNE
  return (u16)(u >> 16);
}

// XOR swizzle for tiles with 128B rows: byte ^= ((row&7)<<4).
__device__ __forceinline__ int swz128(int o) { return o ^ ((o >> 3) & 0x70); }

// async global->LDS, 16B per lane; LDS dest is wave-uniform base (HW adds lane*16).
__device__ __forceinline__ void gload16(const void* g, void* l) {
  __builtin_amdgcn_global_load_lds((const __attribute__((address_space(1))) void*)g,
                                   (__attribute__((address_space(3))) void*)l, 16, 0, 0);
}

// ---------------- fused prep: x->bf16 convert + W_kqv^T + W_proj^T (bf16) ----------------
__global__ __launch_bounds__(256) void prep(const float* __restrict__ x,
                                            const float* __restrict__ Wk,
                                            const float* __restrict__ Wp, u16* __restrict__ xb,
                                            u16* __restrict__ wkt, u16* __restrict__ wpt) {
  __shared__ float tile[64][65];
  const int id = blockIdx.x, tid = threadIdx.x;
  if (id < 2048) {  // convert x: 2^20 float4 elements
    const float4* in4 = reinterpret_cast<const float4*>(x);
    u16x4* out4 = reinterpret_cast<u16x4*>(xb);
    int i = id * 256 + tid;
#pragma unroll
    for (int p = 0; p < 2; ++p, i += 524288) {
      const float4 v = in4[i];
      u16x4 o = {f2bf(v.x), f2bf(v.y), f2bf(v.z), f2bf(v.w)};
      out4[i] = o;
    }
    return;
  }
  const float* in;
  u16* out;
  int R, C, bx, by;
  if (id < 2816) {
    const int t = id - 2048;
    in = Wk; out = wkt; R = 1024; C = 3072; bx = t % 48; by = t / 48;
  } else {
    const int t = id - 2816;
    in = Wp; out = wpt; R = 1024; C = 1024; bx = t & 15; by = t >> 4;
  }
  const int ct = bx * 64, rt = by * 64;
#pragma unroll
  for (int p = 0; p < 4; ++p) {
    int f = p * 256 + tid;
    int row = f >> 4, c4 = (f & 15) << 2;
    const float4 v = *reinterpret_cast<const float4*>(in + (size_t)(rt + row) * C + ct + c4);
    tile[row][c4 + 0] = v.x; tile[row][c4 + 1] = v.y;
    tile[row][c4 + 2] = v.z; tile[row][c4 + 3] = v.w;
  }
  __syncthreads();
#pragma unroll
  for (int p = 0; p < 4; ++p) {
    int g = p * 256 + tid;
    int orow = g >> 4, k4 = (g & 15) << 2;
    u16x4 o = {f2bf(tile[k4 + 0][orow]), f2bf(tile[k4 + 1][orow]),
               f2bf(tile[k4 + 2][orow]), f2bf(tile[k4 + 3][orow])};
    *reinterpret_cast<u16x4*>(out + (size_t)(ct + orow) * R + rt + k4) = o;
  }
}

// ---------------- bf16 GEMM: C[M][N] = A[M][K] @ Bt[N][K]^T (+bias) ----------------
// Staging via global_load_lds w=16; linear LDS dest, pre-swizzled source; readers swz128.
// EPI 0: scatter K/Q to [B][H][S][D], V directly transposed to [B][H][D][S]. EPI 1: fp32 row-major.
template <int EPI>
__global__ __launch_bounds__(256) void gemm_bt(const u16* __restrict__ A,
                                               const u16* __restrict__ Bt,
                                               const float* __restrict__ bias, int M, int N, int K,
                                               float* __restrict__ outF, u16* __restrict__ outK,
                                               u16* __restrict__ outQ, u16* __restrict__ outVt) {
  __shared__ __align__(16) u16 sA[128 * 64];
  __shared__ __align__(16) u16 sB[128 * 64];
  const int tid = threadIdx.x, lane = tid & 63;
  const int wave = tid >> 6, wr = wave >> 1, wc = wave & 1;
  int lin = blockIdx.y * gridDim.x + blockIdx.x;
  const int nwg = gridDim.x * gridDim.y;
  if ((nwg & 7) == 0) {  // bijective XCD-chunked swizzle
    const int cpx = nwg >> 3;
    lin = (lin & 7) * cpx + (lin >> 3);
  }
  const int bm = (lin / gridDim.x) * 128, bn = (lin % gridDim.x) * 128;
  const int r8 = lane >> 3, c16 = (lane & 7) ^ r8;
  f32x4 acc[4][4] = {};
  for (int k0 = 0; k0 < K; k0 += 64) {
#pragma unroll
    for (int i = 0; i < 4; ++i) {
      const int c = wave * 4 + i;
      const int row = c * 8 + r8;
      gload16(A + (size_t)(bm + row) * K + k0 + c16 * 8, (char*)sA + c * 1024);
      gload16(Bt + (size_t)(bn + row) * K + k0 + c16 * 8, (char*)sB + c * 1024);
    }
    __syncthreads();  // vmcnt(0) drain: tile ready
#pragma unroll
    for (int kc = 0; kc < 2; ++kc) {
      bfx8 af[4], bf[4];
#pragma unroll
      for (int mf = 0; mf < 4; ++mf) {
        int o = swz128(((wr * 64 + mf * 16 + (lane & 15)) << 7) + kc * 64 + ((lane >> 4) << 4));
        af[mf] = *reinterpret_cast<const bfx8*>(reinterpret_cast<const char*>(sA) + o);
      }
#pragma unroll
      for (int nf = 0; nf < 4; ++nf) {
        int o = swz128(((wc * 64 + nf * 16 + (lane & 15)) << 7) + kc * 64 + ((lane >> 4) << 4));
        bf[nf] = *reinterpret_cast<const bfx8*>(reinterpret_cast<const char*>(sB) + o);
      }
#pragma unroll
      for (int mf = 0; mf < 4; ++mf)
#pragma unroll
        for (int nf = 0; nf < 4; ++nf)
          acc[mf][nf] = __builtin_amdgcn_mfma_f32_16x16x32_bf16(af[mf], bf[nf], acc[mf][nf], 0, 0, 0);
    }
    __syncthreads();  // protect LDS before next stage
  }
#pragma unroll
  for (int mf = 0; mf < 4; ++mf)
#pragma unroll
    for (int nf = 0; nf < 4; ++nf)
#pragma unroll
      for (int r = 0; r < 4; ++r) {
        const int row = bm + wr * 64 + mf * 16 + ((lane >> 4) << 2) + r;
        const int col = bn + wc * 64 + nf * 16 + (lane & 15);
        const float v = acc[mf][nf][r] + bias[col];
        if (EPI == 1) {
          outF[(size_t)row * N + col] = v;
        } else {
          const int chunk = col >> 10, w = col & 1023, h = w >> 6, dd = w & 63;
          const int b = row >> 11, s = row & 2047;
          const int bh = b * H_ + h;
          if (chunk == 0)
            outK[((size_t)bh * S_ + s) * D_ + dd] = f2bf(v);
          else if (chunk == 1)
            outQ[((size_t)bh * S_ + s) * D_ + dd] = f2bf(v);
          else
            outVt[((size_t)bh * D_ + dd) * S_ + s] = f2bf(v);  // fused V transpose
        }
      }
}

// ---------------- flash attention with ALiBi, causal ----------------
// QBLK=64 (wave owns 16 q rows), KVBLK=64, 1024 blocks (4/CU -> 4 waves/SIMD).
// id -> (bh,qi) so each CU's 4 blocks get qi {31-r, r, 31-r, r}: 66 tiles/CU uniform.
// tt = mfma_16x16x32(K,Q): lane(g,q) holds S[key=nf*16+4g+r][q]. exp2-domain softmax,
// ALiBi row-term dropped (cancels), defer-max (T13). P bounced via wave-private swizzled sP.
__global__ __launch_bounds__(256, 4) void attn_alibi(const u16* __restrict__ Q,
                                                     const u16* __restrict__ Kb,
                                                     const u16* __restrict__ Vt,
                                                     const float* __restrict__ slopes,
                                                     u16* __restrict__ Y) {
  __shared__ __align__(16) u16 sK[2][4096];
  __shared__ __align__(16) u16 sV[2][4096];
  __shared__ __align__(16) __bf16 sP[4][16 * 64];
  const int id = blockIdx.x;
  const int hi2 = id >> 8, rem = id & 255;
  const int r5 = rem & 31;
  const int qi = (hi2 & 1) ? r5 : 31 - r5;
  const int bh = (hi2 << 3) + (rem >> 5);
  const int b = bh >> 4, h = bh & 15;
  const int tid = threadIdx.x, lane = tid & 63, wave = tid >> 6;
  const int q = lane & 15, g = lane >> 4;
  const int q0 = qi * 64;
  const int w0 = q0 + wave * 16;
  const float L2E = 1.44269504089f;
  const float SCALE = 0.125f * L2E;
  const float sl2 = slopes[h] * L2E;
  const size_t headSD = (size_t)bh * (S_ * D_);
  const size_t headDS = (size_t)bh * (D_ * S_);
  const int nt = qi + 1;
  const int r8 = lane >> 3, c16 = (lane & 7) ^ r8;

  // Q fragments (B-operand): lane holds q row w0+q, k = kc*32 + g*8 + e
  bfx8 qf[2];
  {
    const u16* qp = Q + headSD + (size_t)(w0 + q) * D_ + g * 8;
    qf[0] = *reinterpret_cast<const bfx8*>(qp);
    qf[1] = *reinterpret_cast<const bfx8*>(qp + 32);
  }
  // key bias (log2 domain), row-term cancelled
  f32x4 base[4];
#pragma unroll
  for (int nf = 0; nf < 4; ++nf)
#pragma unroll
    for (int r = 0; r < 4; ++r) base[nf][r] = sl2 * (float)(nf * 16 + 4 * g + r);
  const int ir0 = wave * 16 + q;  // diagonal-tile mask boundary (key-local > ir0 masked)

  float m = 0.f, l = 0.f;
  f32x4 oT[4] = {};

  auto stage = [&](int t, int buf) {
#pragma unroll
    for (int i = 0; i < 2; ++i) {
      const int c = wave * 2 + i;  // chunk 0..7 of 8KB tile
      const int row = c * 8 + r8;  // K: key row; V: d row
      gload16(Kb + headSD + (size_t)t * 4096 + row * 64 + c16 * 8, (char*)sK[buf] + c * 1024);
      gload16(Vt + headDS + (size_t)row * S_ + t * 64 + c16 * 8, (char*)sV[buf] + c * 1024);
    }
  };

  stage(0, 0);
  __syncthreads();
  int cur = 0;
  for (int t = 0; t < nt; ++t) {
    if (t + 1 < nt) stage(t + 1, cur ^ 1);  // in flight across compute; drained at barrier
    const char* sKc = reinterpret_cast<const char*>(sK[cur]);
    const char* sVc = reinterpret_cast<const char*>(sV[cur]);
    f32x4 tt[4] = {};
#pragma unroll
    for (int kc = 0; kc < 2; ++kc)
#pragma unroll
      for (int nf = 0; nf < 4; ++nf) {
        const bfx8 kf =
            *reinterpret_cast<const bfx8*>(sKc + swz128(((nf * 16 + q) << 7) + kc * 64 + (g << 4)));
        tt[nf] = __builtin_amdgcn_mfma_f32_16x16x32_bf16(kf, qf[kc], tt[nf], 0, 0, 0);
      }
    const float tb = sl2 * (float)(t * 64);
    const bool last = (t == nt - 1);
    float rmax = -3.0e38f;
#pragma unroll
    for (int nf = 0; nf < 4; ++nf)
#pragma unroll
      for (int r = 0; r < 4; ++r) {
        float sv = fmaf(tt[nf][r], SCALE, base[nf][r] + tb);
        if (last && (nf * 16 + 4 * g + r > ir0)) sv = -3.0e38f;
        tt[nf][r] = sv;
        rmax = fmaxf(rmax, sv);
      }
    rmax = fmaxf(rmax, __shfl_xor(rmax, 16));
    rmax = fmaxf(rmax, __shfl_xor(rmax, 32));
    if (!__all(rmax <= m + 12.0f)) {  // defer-max (T13), log2 domain
      const float mnew = fmaxf(m, rmax);
      const float corr = __builtin_amdgcn_exp2f(m - mnew);
      m = mnew;
      l *= corr;
#pragma unroll
      for (int nf = 0; nf < 4; ++nf) oT[nf] *= corr;
    }
    float rsum = 0.f;
#pragma unroll
    for (int nf = 0; nf < 4; ++nf)
#pragma unroll
      for (int r = 0; r < 4; ++r) {
        const float pe = __builtin_amdgcn_exp2f(tt[nf][r] - m);
        tt[nf][r] = pe;
        rsum += pe;
      }
    rsum += __shfl_xor(rsum, 16);
    rsum += __shfl_xor(rsum, 32);
    l += rsum;
    // P -> wave-private swizzled sP (row q, 128B rows); wave-internal lgkm ordering, no barrier
    char* pw = reinterpret_cast<char*>(sP[wave]);
#pragma unroll
    for (int nf = 0; nf < 4; ++nf) {
      bfx4 w = {(__bf16)tt[nf][0], (__bf16)tt[nf][1], (__bf16)tt[nf][2], (__bf16)tt[nf][3]};
      *reinterpret_cast<bfx4*>(pw + swz128((q << 7) + nf * 32 + g * 8)) = w;
    }
    bfx8 pa[2];
#pragma unroll
    for (int kc = 0; kc < 2; ++kc)
      pa[kc] = *reinterpret_cast<const bfx8*>(pw + swz128((q << 7) + kc * 64 + (g << 4)));
#pragma unroll
    for (int kc = 0; kc < 2; ++kc)
#pragma unroll
      for (int nf = 0; nf < 4; ++nf) {
        const bfx8 vf =
            *reinterpret_cast<const bfx8*>(sVc + swz128(((nf * 16 + q) << 7) + kc * 64 + (g << 4)));
        oT[nf] = __builtin_amdgcn_mfma_f32_16x16x32_bf16(vf, pa[kc], oT[nf], 0, 0, 0);
      }
    __syncthreads();  // drains prefetch vmcnt; protects sK/sV swap
    cur ^= 1;
  }
  const float rl = 1.0f / l;
  const int row = w0 + q;
#pragma unroll
  for (int nf = 0; nf < 4; ++nf) {
    bfx4 w = {(__bf16)(oT[nf][0] * rl), (__bf16)(oT[nf][1] * rl), (__bf16)(oT[nf][2] * rl),
              (__bf16)(oT[nf][3] * rl)};
    const int col = h * 64 + nf * 16 + g * 4;
    *reinterpret_cast<bfx4*>(reinterpret_cast<char*>(Y) + (((size_t)b * S_ + row) * E_ + col) * 2) =
        w;
  }
}

extern "C" void kernel_launch(void* const* d_in, const int* in_sizes, int n_in, void* d_out,
                              int out_size, void* d_ws, size_t ws_size, hipStream_t stream) {
  (void)in_sizes; (void)n_in; (void)out_size; (void)ws_size;
  const float* x = (const float*)d_in[0];
  const float* Wkqv = (const float*)d_in[1];
  const float* bkqv = (const float*)d_in[2];
  const float* Wproj = (const float*)d_in[3];
  const float* bproj = (const float*)d_in[4];
  const float* slopes = (const float*)d_in[5];
  float* out = (float*)d_out;

  const size_t MBE = (size_t)4096 * 1024;
  u16* xb = (u16*)d_ws;                       // x bf16              [4096][1024]
  u16* wkqvt = xb + MBE;                      // W_kqv^T bf16        [3072][1024]
  u16* wprojt = wkqvt + (size_t)3072 * 1024;  // W_proj^T bf16       [1024][1024]
  u16* kbuf = wprojt + (size_t)1024 * 1024;   // K   [B][H][S][D]
  u16* qbuf = kbuf + MBE;                     // Q   [B][H][S][D]
  u16* vtbuf = qbuf + MBE;                    // V^T [B][H][D][S]
  u16* ybuf = vtbuf + MBE;                    // attn out [B][S][E]

  prep<<<dim3(3072), dim3(256), 0, stream>>>(x, Wkqv, Wproj, xb, wkqvt, wprojt);
  gemm_bt<0><<<dim3(24, 32), dim3(256), 0, stream>>>(xb, wkqvt, bkqv, 4096, 3072, 1024,
                                                     (float*)nullptr, kbuf, qbuf, vtbuf);
  attn_alibi<<<dim3(1024), dim3(256), 0, stream>>>(qbuf, kbuf, vtbuf, slopes, ybuf);
  gemm_bt<1><<<dim3(8, 32), dim3(256), 0, stream>>>(ybuf, wprojt, bproj, 4096, 1024, 1024, out,
                                                    nullptr, nullptr, nullptr);
}

// Round 7
// 118.948 us; speedup vs baseline: 1.3430x; 1.0298x over previous
//
#include <hip/hip_runtime.h>

typedef unsigned short u16;
typedef float f32x4 __attribute__((ext_vector_type(4)));
typedef __bf16 bfx8 __attribute__((ext_vector_type(8)));
typedef __bf16 bfx4 __attribute__((ext_vector_type(4)));
typedef u16 u16x8 __attribute__((ext_vector_type(8)));
typedef u16 u16x4 __attribute__((ext_vector_type(4)));

#define B_ 2
#define S_ 2048
#define E_ 1024
#define H_ 16
#define D_ 64

__device__ __forceinline__ u16 f2bf(float f) {
  unsigned u = __float_as_uint(f);
  u = u + 0x7FFFu + ((u >> 16) & 1u);  // RNE
  return (u16)(u >> 16);
}

// XOR swizzle for tiles with 128B rows: byte ^= ((row&7)<<4).
__device__ __forceinline__ int swz128(int o) { return o ^ ((o >> 3) & 0x70); }

// async global->LDS, 16B per lane; LDS dest is wave-uniform base (HW adds lane*16).
__device__ __forceinline__ void gload16(const void* g, void* l) {
  __builtin_amdgcn_global_load_lds((const __attribute__((address_space(1))) void*)g,
                                   (__attribute__((address_space(3))) void*)l, 16, 0, 0);
}

// ---------------- fused prep: x->bf16 convert + W_kqv^T + W_proj^T (bf16) ----------------
__global__ __launch_bounds__(256) void prep(const float* __restrict__ x,
                                            const float* __restrict__ Wk,
                                            const float* __restrict__ Wp, u16* __restrict__ xb,
                                            u16* __restrict__ wkt, u16* __restrict__ wpt) {
  __shared__ float tile[64][65];
  const int id = blockIdx.x, tid = threadIdx.x;
  if (id < 2048) {  // convert x: 2^20 float4 elements
    const float4* in4 = reinterpret_cast<const float4*>(x);
    u16x4* out4 = reinterpret_cast<u16x4*>(xb);
    int i = id * 256 + tid;
#pragma unroll
    for (int p = 0; p < 2; ++p, i += 524288) {
      const float4 v = in4[i];
      u16x4 o = {f2bf(v.x), f2bf(v.y), f2bf(v.z), f2bf(v.w)};
      out4[i] = o;
    }
    return;
  }
  const float* in;
  u16* out;
  int R, C, bx, by;
  if (id < 2816) {
    const int t = id - 2048;
    in = Wk; out = wkt; R = 1024; C = 3072; bx = t % 48; by = t / 48;
  } else {
    const int t = id - 2816;
    in = Wp; out = wpt; R = 1024; C = 1024; bx = t & 15; by = t >> 4;
  }
  const int ct = bx * 64, rt = by * 64;
#pragma unroll
  for (int p = 0; p < 4; ++p) {
    int f = p * 256 + tid;
    int row = f >> 4, c4 = (f & 15) << 2;
    const float4 v = *reinterpret_cast<const float4*>(in + (size_t)(rt + row) * C + ct + c4);
    tile[row][c4 + 0] = v.x; tile[row][c4 + 1] = v.y;
    tile[row][c4 + 2] = v.z; tile[row][c4 + 3] = v.w;
  }
  __syncthreads();
#pragma unroll
  for (int p = 0; p < 4; ++p) {
    int g = p * 256 + tid;
    int orow = g >> 4, k4 = (g & 15) << 2;
    u16x4 o = {f2bf(tile[k4 + 0][orow]), f2bf(tile[k4 + 1][orow]),
               f2bf(tile[k4 + 2][orow]), f2bf(tile[k4 + 3][orow])};
    *reinterpret_cast<u16x4*>(out + (size_t)(ct + orow) * R + rt + k4) = o;
  }
}

// ---------------- bf16 GEMM (4 waves): C = A @ Bt^T + bias; EPI0 scatters K/Q/V^T ----------------
__global__ __launch_bounds__(256) void gemm_kqv(const u16* __restrict__ A,
                                                const u16* __restrict__ Bt,
                                                const float* __restrict__ bias, int M, int N, int K,
                                                u16* __restrict__ outK, u16* __restrict__ outQ,
                                                u16* __restrict__ outVt) {
  __shared__ __align__(16) u16 sA[128 * 64];
  __shared__ __align__(16) u16 sB[128 * 64];
  const int tid = threadIdx.x, lane = tid & 63;
  const int wave = tid >> 6, wr = wave >> 1, wc = wave & 1;
  int lin = blockIdx.y * gridDim.x + blockIdx.x;
  const int nwg = gridDim.x * gridDim.y;
  if ((nwg & 7) == 0) {  // bijective XCD-chunked swizzle
    const int cpx = nwg >> 3;
    lin = (lin & 7) * cpx + (lin >> 3);
  }
  const int bm = (lin / gridDim.x) * 128, bn = (lin % gridDim.x) * 128;
  const int r8 = lane >> 3, c16 = (lane & 7) ^ r8;
  f32x4 acc[4][4] = {};
  for (int k0 = 0; k0 < K; k0 += 64) {
#pragma unroll
    for (int i = 0; i < 4; ++i) {
      const int c = wave * 4 + i;
      const int row = c * 8 + r8;
      gload16(A + (size_t)(bm + row) * K + k0 + c16 * 8, (char*)sA + c * 1024);
      gload16(Bt + (size_t)(bn + row) * K + k0 + c16 * 8, (char*)sB + c * 1024);
    }
    __syncthreads();
#pragma unroll
    for (int kc = 0; kc < 2; ++kc) {
      bfx8 af[4], bf[4];
#pragma unroll
      for (int mf = 0; mf < 4; ++mf) {
        int o = swz128(((wr * 64 + mf * 16 + (lane & 15)) << 7) + kc * 64 + ((lane >> 4) << 4));
        af[mf] = *reinterpret_cast<const bfx8*>(reinterpret_cast<const char*>(sA) + o);
      }
#pragma unroll
      for (int nf = 0; nf < 4; ++nf) {
        int o = swz128(((wc * 64 + nf * 16 + (lane & 15)) << 7) + kc * 64 + ((lane >> 4) << 4));
        bf[nf] = *reinterpret_cast<const bfx8*>(reinterpret_cast<const char*>(sB) + o);
      }
#pragma unroll
      for (int mf = 0; mf < 4; ++mf)
#pragma unroll
        for (int nf = 0; nf < 4; ++nf)
          acc[mf][nf] = __builtin_amdgcn_mfma_f32_16x16x32_bf16(af[mf], bf[nf], acc[mf][nf], 0, 0, 0);
    }
    __syncthreads();
  }
#pragma unroll
  for (int mf = 0; mf < 4; ++mf)
#pragma unroll
    for (int nf = 0; nf < 4; ++nf)
#pragma unroll
      for (int r = 0; r < 4; ++r) {
        const int row = bm + wr * 64 + mf * 16 + ((lane >> 4) << 2) + r;
        const int col = bn + wc * 64 + nf * 16 + (lane & 15);
        const float v = acc[mf][nf][r] + bias[col];
        const int chunk = col >> 10, w = col & 1023, h = w >> 6, dd = w & 63;
        const int b = row >> 11, s = row & 2047;
        const int bh = b * H_ + h;
        if (chunk == 0)
          outK[((size_t)bh * S_ + s) * D_ + dd] = f2bf(v);
        else if (chunk == 1)
          outQ[((size_t)bh * S_ + s) * D_ + dd] = f2bf(v);
        else
          outVt[((size_t)bh * D_ + dd) * S_ + s] = f2bf(v);  // fused V transpose
      }
}

// ---------------- proj GEMM (8 waves, 512 thr): fp32 out row-major ----------------
// 128^2 tile; at 1 block/CU this gives 2 waves/SIMD (vs 1 for the 4-wave version).
__global__ __launch_bounds__(512) void gemm_proj(const u16* __restrict__ A,
                                                 const u16* __restrict__ Bt,
                                                 const float* __restrict__ bias, int M, int N,
                                                 int K, float* __restrict__ outF) {
  __shared__ __align__(16) u16 sA[128 * 64];
  __shared__ __align__(16) u16 sB[128 * 64];
  const int tid = threadIdx.x, lane = tid & 63;
  const int wave = tid >> 6, wr = wave >> 2, wc = wave & 3;  // 2x4 waves of 64x32
  int lin = blockIdx.y * gridDim.x + blockIdx.x;
  const int nwg = gridDim.x * gridDim.y;
  if ((nwg & 7) == 0) {
    const int cpx = nwg >> 3;
    lin = (lin & 7) * cpx + (lin >> 3);
  }
  const int bm = (lin / gridDim.x) * 128, bn = (lin % gridDim.x) * 128;
  const int r8 = lane >> 3, c16 = (lane & 7) ^ r8;
  f32x4 acc[4][2] = {};
  for (int k0 = 0; k0 < K; k0 += 64) {
#pragma unroll
    for (int i = 0; i < 2; ++i) {
      const int c = wave * 2 + i;  // 16 chunks of 1KB
      const int row = c * 8 + r8;
      gload16(A + (size_t)(bm + row) * K + k0 + c16 * 8, (char*)sA + c * 1024);
      gload16(Bt + (size_t)(bn + row) * K + k0 + c16 * 8, (char*)sB + c * 1024);
    }
    __syncthreads();
#pragma unroll
    for (int kc = 0; kc < 2; ++kc) {
      bfx8 af[4], bf[2];
#pragma unroll
      for (int mf = 0; mf < 4; ++mf) {
        int o = swz128(((wr * 64 + mf * 16 + (lane & 15)) << 7) + kc * 64 + ((lane >> 4) << 4));
        af[mf] = *reinterpret_cast<const bfx8*>(reinterpret_cast<const char*>(sA) + o);
      }
#pragma unroll
      for (int nf = 0; nf < 2; ++nf) {
        int o = swz128(((wc * 32 + nf * 16 + (lane & 15)) << 7) + kc * 64 + ((lane >> 4) << 4));
        bf[nf] = *reinterpret_cast<const bfx8*>(reinterpret_cast<const char*>(sB) + o);
      }
#pragma unroll
      for (int mf = 0; mf < 4; ++mf)
#pragma unroll
        for (int nf = 0; nf < 2; ++nf)
          acc[mf][nf] = __builtin_amdgcn_mfma_f32_16x16x32_bf16(af[mf], bf[nf], acc[mf][nf], 0, 0, 0);
    }
    __syncthreads();
  }
#pragma unroll
  for (int mf = 0; mf < 4; ++mf)
#pragma unroll
    for (int nf = 0; nf < 2; ++nf)
#pragma unroll
      for (int r = 0; r < 4; ++r) {
        const int row = bm + wr * 64 + mf * 16 + ((lane >> 4) << 2) + r;
        const int col = bn + wc * 32 + nf * 16 + (lane & 15);
        outF[(size_t)row * N + col] = acc[mf][nf][r] + bias[col];
      }
}

// ---------------- flash attention with ALiBi, causal ----------------
// QBLK=64, KVBLK=64, 1024 blocks (4/CU). Swapped-operand 16x16 MFMA, exp2-domain softmax.
// l computed by a ones-A-fragment MFMA riding the PV cluster (every lane gets l, no shuffles).
// Non-diagonal tiles: raw-max + upper bound (SCALE*rawmax + max bias) -> fused bias+exp2 pass;
// the overshoot only scales P and l by the same factor (ratio exact, bf16 rel-precision kept).
__global__ __launch_bounds__(256, 4) void attn_alibi(const u16* __restrict__ Q,
                                                     const u16* __restrict__ Kb,
                                                     const u16* __restrict__ Vt,
                                                     const float* __restrict__ slopes,
                                                     u16* __restrict__ Y) {
  __shared__ __align__(16) u16 sK[2][4096];
  __shared__ __align__(16) u16 sV[2][4096];
  __shared__ __align__(16) __bf16 sP[4][16 * 64];
  const int id = blockIdx.x;
  const int hi2 = id >> 8, rem = id & 255;
  const int r5 = rem & 31;
  const int qi = (hi2 & 1) ? r5 : 31 - r5;
  const int bh = (hi2 << 3) + (rem >> 5);
  const int b = bh >> 4, h = bh & 15;
  const int tid = threadIdx.x, lane = tid & 63, wave = tid >> 6;
  const int q = lane & 15, g = lane >> 4;
  const int q0 = qi * 64;
  const int w0 = q0 + wave * 16;
  const float L2E = 1.44269504089f;
  const float SCALE = 0.125f * L2E;
  const float sl2 = slopes[h] * L2E;
  const size_t headSD = (size_t)bh * (S_ * D_);
  const size_t headDS = (size_t)bh * (D_ * S_);
  const int nt = qi + 1;
  const int r8 = lane >> 3, c16 = (lane & 7) ^ r8;

  bfx8 qf[2];
  {
    const u16* qp = Q + headSD + (size_t)(w0 + q) * D_ + g * 8;
    qf[0] = *reinterpret_cast<const bfx8*>(qp);
    qf[1] = *reinterpret_cast<const bfx8*>(qp + 32);
  }
  bfx8 onesf;
#pragma unroll
  for (int j = 0; j < 8; ++j) onesf[j] = (__bf16)1.0f;
  f32x4 base[4];
#pragma unroll
  for (int nf = 0; nf < 4; ++nf)
#pragma unroll
    for (int r = 0; r < 4; ++r) base[nf][r] = sl2 * (float)(nf * 16 + 4 * g + r);
  const int ir0 = wave * 16 + q;  // diagonal-tile mask boundary

  float m = 0.f;
  f32x4 oT[4] = {};
  f32x4 oX = {};  // l accumulator (all components equal l)

  auto stage = [&](int t, int buf) {
#pragma unroll
    for (int i = 0; i < 2; ++i) {
      const int c = wave * 2 + i;
      const int row = c * 8 + r8;
      gload16(Kb + headSD + (size_t)t * 4096 + row * 64 + c16 * 8, (char*)sK[buf] + c * 1024);
      gload16(Vt + headDS + (size_t)row * S_ + t * 64 + c16 * 8, (char*)sV[buf] + c * 1024);
    }
  };

  stage(0, 0);
  __syncthreads();
  int cur = 0;
  for (int t = 0; t < nt; ++t) {
    if (t + 1 < nt) stage(t + 1, cur ^ 1);
    const char* sKc = reinterpret_cast<const char*>(sK[cur]);
    const char* sVc = reinterpret_cast<const char*>(sV[cur]);
    f32x4 tt[4] = {};
    __builtin_amdgcn_s_setprio(1);
#pragma unroll
    for (int kc = 0; kc < 2; ++kc)
#pragma unroll
      for (int nf = 0; nf < 4; ++nf) {
        const bfx8 kf =
            *reinterpret_cast<const bfx8*>(sKc + swz128(((nf * 16 + q) << 7) + kc * 64 + (g << 4)));
        tt[nf] = __builtin_amdgcn_mfma_f32_16x16x32_bf16(kf, qf[kc], tt[nf], 0, 0, 0);
      }
    __builtin_amdgcn_s_setprio(0);
    const float tb = sl2 * (float)(t * 64);
    if (t != nt - 1) {
      // ---- non-diagonal tile: raw max + upper bound, fused bias+exp2 ----
      float rmax = -3.0e38f;
#pragma unroll
      for (int nf = 0; nf < 4; ++nf)
#pragma unroll
        for (int r = 0; r < 4; ++r) rmax = fmaxf(rmax, tt[nf][r]);
      rmax = fmaxf(rmax, __shfl_xor(rmax, 16));
      rmax = fmaxf(rmax, __shfl_xor(rmax, 32));
      const float bound = fmaf(rmax, SCALE, tb + sl2 * 63.f);  // >= true biased row max
      if (!__all(bound <= m + 12.0f)) {
        const float mnew = fmaxf(m, bound);
        const float corr = __builtin_amdgcn_exp2f(m - mnew);
        m = mnew;
#pragma unroll
        for (int nf = 0; nf < 4; ++nf) oT[nf] *= corr;
        oX *= corr;
      }
      const float tbm = tb - m;
#pragma unroll
      for (int nf = 0; nf < 4; ++nf) {
        const f32x4 bb = base[nf] + tbm;
#pragma unroll
        for (int r = 0; r < 4; ++r)
          tt[nf][r] = __builtin_amdgcn_exp2f(fmaf(tt[nf][r], SCALE, bb[r]));
      }
    } else {
      // ---- diagonal tile: exact per-element bias + causal mask ----
      float rmax = -3.0e38f;
#pragma unroll
      for (int nf = 0; nf < 4; ++nf)
#pragma unroll
        for (int r = 0; r < 4; ++r) {
          float sv = fmaf(tt[nf][r], SCALE, base[nf][r] + tb);
          if (nf * 16 + 4 * g + r > ir0) sv = -3.0e38f;
          tt[nf][r] = sv;
          rmax = fmaxf(rmax, sv);
        }
      rmax = fmaxf(rmax, __shfl_xor(rmax, 16));
      rmax = fmaxf(rmax, __shfl_xor(rmax, 32));
      if (!__all(rmax <= m + 12.0f)) {
        const float mnew = fmaxf(m, rmax);
        const float corr = __builtin_amdgcn_exp2f(m - mnew);
        m = mnew;
#pragma unroll
        for (int nf = 0; nf < 4; ++nf) oT[nf] *= corr;
        oX *= corr;
      }
#pragma unroll
      for (int nf = 0; nf < 4; ++nf)
#pragma unroll
        for (int r = 0; r < 4; ++r) tt[nf][r] = __builtin_amdgcn_exp2f(tt[nf][r] - m);
    }
    // P -> wave-private swizzled sP; wave-internal lgkm ordering, no barrier
    char* pw = reinterpret_cast<char*>(sP[wave]);
#pragma unroll
    for (int nf = 0; nf < 4; ++nf) {
      bfx4 w = {(__bf16)tt[nf][0], (__bf16)tt[nf][1], (__bf16)tt[nf][2], (__bf16)tt[nf][3]};
      *reinterpret_cast<bfx4*>(pw + swz128((q << 7) + nf * 32 + g * 8)) = w;
    }
    bfx8 pa[2];
#pragma unroll
    for (int kc = 0; kc < 2; ++kc)
      pa[kc] = *reinterpret_cast<const bfx8*>(pw + swz128((q << 7) + kc * 64 + (g << 4)));
    __builtin_amdgcn_s_setprio(1);
#pragma unroll
    for (int kc = 0; kc < 2; ++kc) {
#pragma unroll
      for (int nf = 0; nf < 4; ++nf) {
        const bfx8 vf =
            *reinterpret_cast<const bfx8*>(sVc + swz128(((nf * 16 + q) << 7) + kc * 64 + (g << 4)));
        oT[nf] = __builtin_amdgcn_mfma_f32_16x16x32_bf16(vf, pa[kc], oT[nf], 0, 0, 0);
      }
      oX = __builtin_amdgcn_mfma_f32_16x16x32_bf16(onesf, pa[kc], oX, 0, 0, 0);  // l rides PV
    }
    __builtin_amdgcn_s_setprio(0);
    __syncthreads();
    cur ^= 1;
  }
  const float rl = 1.0f / oX[0];
  const int row = w0 + q;
#pragma unroll
  for (int nf = 0; nf < 4; ++nf) {
    bfx4 w = {(__bf16)(oT[nf][0] * rl), (__bf16)(oT[nf][1] * rl), (__bf16)(oT[nf][2] * rl),
              (__bf16)(oT[nf][3] * rl)};
    const int col = h * 64 + nf * 16 + g * 4;
    *reinterpret_cast<bfx4*>(reinterpret_cast<char*>(Y) + (((size_t)b * S_ + row) * E_ + col) * 2) =
        w;
  }
}

extern "C" void kernel_launch(void* const* d_in, const int* in_sizes, int n_in, void* d_out,
                              int out_size, void* d_ws, size_t ws_size, hipStream_t stream) {
  (void)in_sizes; (void)n_in; (void)out_size; (void)ws_size;
  const float* x = (const float*)d_in[0];
  const float* Wkqv = (const float*)d_in[1];
  const float* bkqv = (const float*)d_in[2];
  const float* Wproj = (const float*)d_in[3];
  const float* bproj = (const float*)d_in[4];
  const float* slopes = (const float*)d_in[5];
  float* out = (float*)d_out;

  const size_t MBE = (size_t)4096 * 1024;
  u16* xb = (u16*)d_ws;                       // x bf16              [4096][1024]
  u16* wkqvt = xb + MBE;                      // W_kqv^T bf16        [3072][1024]
  u16* wprojt = wkqvt + (size_t)3072 * 1024;  // W_proj^T bf16       [1024][1024]
  u16* kbuf = wprojt + (size_t)1024 * 1024;   // K   [B][H][S][D]
  u16* qbuf = kbuf + MBE;                     // Q   [B][H][S][D]
  u16* vtbuf = qbuf + MBE;                    // V^T [B][H][D][S]
  u16* ybuf = vtbuf + MBE;                    // attn out [B][S][E]

  prep<<<dim3(3072), dim3(256), 0, stream>>>(x, Wkqv, Wproj, xb, wkqvt, wprojt);
  gemm_kqv<<<dim3(24, 32), dim3(256), 0, stream>>>(xb, wkqvt, bkqv, 4096, 3072, 1024, kbuf, qbuf,
                                                   vtbuf);
  attn_alibi<<<dim3(1024), dim3(256), 0, stream>>>(qbuf, kbuf, vtbuf, slopes, ybuf);
  gemm_proj<<<dim3(8, 32), dim3(512), 0, stream>>>(ybuf, wprojt, bproj, 4096, 1024, 1024, out);
}

// Round 8
// 118.296 us; speedup vs baseline: 1.3504x; 1.0055x over previous
//
#include <hip/hip_runtime.h>

typedef unsigned short u16;
typedef float f32x4 __attribute__((ext_vector_type(4)));
typedef __bf16 bfx8 __attribute__((ext_vector_type(8)));
typedef __bf16 bfx4 __attribute__((ext_vector_type(4)));
typedef u16 u16x8 __attribute__((ext_vector_type(8)));
typedef u16 u16x4 __attribute__((ext_vector_type(4)));

#define B_ 2
#define S_ 2048
#define E_ 1024
#define H_ 16
#define D_ 64

__device__ __forceinline__ u16 f2bf(float f) {
  unsigned u = __float_as_uint(f);
  u = u + 0x7FFFu + ((u >> 16) & 1u);  // RNE
  return (u16)(u >> 16);
}

// XOR swizzle for tiles with 128B rows: byte ^= ((row&7)<<4).
__device__ __forceinline__ int swz128(int o) { return o ^ ((o >> 3) & 0x70); }

// async global->LDS, 16B per lane; LDS dest is wave-uniform base (HW adds lane*16).
__device__ __forceinline__ void gload16(const void* g, void* l) {
  __builtin_amdgcn_global_load_lds((const __attribute__((address_space(1))) void*)g,
                                   (__attribute__((address_space(3))) void*)l, 16, 0, 0);
}

// ---------------- fused prep: x->bf16 convert + W_kqv^T + W_proj^T (bf16) ----------------
__global__ __launch_bounds__(256) void prep(const float* __restrict__ x,
                                            const float* __restrict__ Wk,
                                            const float* __restrict__ Wp, u16* __restrict__ xb,
                                            u16* __restrict__ wkt, u16* __restrict__ wpt) {
  __shared__ float tile[64][65];
  const int id = blockIdx.x, tid = threadIdx.x;
  if (id < 2048) {  // convert x: 2^20 float4 elements
    const float4* in4 = reinterpret_cast<const float4*>(x);
    u16x4* out4 = reinterpret_cast<u16x4*>(xb);
    int i = id * 256 + tid;
#pragma unroll
    for (int p = 0; p < 2; ++p, i += 524288) {
      const float4 v = in4[i];
      u16x4 o = {f2bf(v.x), f2bf(v.y), f2bf(v.z), f2bf(v.w)};
      out4[i] = o;
    }
    return;
  }
  const float* in;
  u16* out;
  int R, C, bx, by;
  if (id < 2816) {
    const int t = id - 2048;
    in = Wk; out = wkt; R = 1024; C = 3072; bx = t % 48; by = t / 48;
  } else {
    const int t = id - 2816;
    in = Wp; out = wpt; R = 1024; C = 1024; bx = t & 15; by = t >> 4;
  }
  const int ct = bx * 64, rt = by * 64;
#pragma unroll
  for (int p = 0; p < 4; ++p) {
    int f = p * 256 + tid;
    int row = f >> 4, c4 = (f & 15) << 2;
    const float4 v = *reinterpret_cast<const float4*>(in + (size_t)(rt + row) * C + ct + c4);
    tile[row][c4 + 0] = v.x; tile[row][c4 + 1] = v.y;
    tile[row][c4 + 2] = v.z; tile[row][c4 + 3] = v.w;
  }
  __syncthreads();
#pragma unroll
  for (int p = 0; p < 4; ++p) {
    int g = p * 256 + tid;
    int orow = g >> 4, k4 = (g & 15) << 2;
    u16x4 o = {f2bf(tile[k4 + 0][orow]), f2bf(tile[k4 + 1][orow]),
               f2bf(tile[k4 + 2][orow]), f2bf(tile[k4 + 3][orow])};
    *reinterpret_cast<u16x4*>(out + (size_t)(ct + orow) * R + rt + k4) = o;
  }
}

// ---------------- bf16 GEMM (4 waves): C = A @ Bt^T + bias; EPI0 scatters K/Q/V^T ----------------
__global__ __launch_bounds__(256) void gemm_kqv(const u16* __restrict__ A,
                                                const u16* __restrict__ Bt,
                                                const float* __restrict__ bias, int M, int N, int K,
                                                u16* __restrict__ outK, u16* __restrict__ outQ,
                                                u16* __restrict__ outVt) {
  __shared__ __align__(16) u16 sA[128 * 64];
  __shared__ __align__(16) u16 sB[128 * 64];
  const int tid = threadIdx.x, lane = tid & 63;
  const int wave = tid >> 6, wr = wave >> 1, wc = wave & 1;
  int lin = blockIdx.y * gridDim.x + blockIdx.x;
  const int nwg = gridDim.x * gridDim.y;
  if ((nwg & 7) == 0) {  // bijective XCD-chunked swizzle
    const int cpx = nwg >> 3;
    lin = (lin & 7) * cpx + (lin >> 3);
  }
  const int bm = (lin / gridDim.x) * 128, bn = (lin % gridDim.x) * 128;
  const int r8 = lane >> 3, c16 = (lane & 7) ^ r8;
  f32x4 acc[4][4] = {};
  for (int k0 = 0; k0 < K; k0 += 64) {
#pragma unroll
    for (int i = 0; i < 4; ++i) {
      const int c = wave * 4 + i;
      const int row = c * 8 + r8;
      gload16(A + (size_t)(bm + row) * K + k0 + c16 * 8, (char*)sA + c * 1024);
      gload16(Bt + (size_t)(bn + row) * K + k0 + c16 * 8, (char*)sB + c * 1024);
    }
    __syncthreads();
#pragma unroll
    for (int kc = 0; kc < 2; ++kc) {
      bfx8 af[4], bf[4];
#pragma unroll
      for (int mf = 0; mf < 4; ++mf) {
        int o = swz128(((wr * 64 + mf * 16 + (lane & 15)) << 7) + kc * 64 + ((lane >> 4) << 4));
        af[mf] = *reinterpret_cast<const bfx8*>(reinterpret_cast<const char*>(sA) + o);
      }
#pragma unroll
      for (int nf = 0; nf < 4; ++nf) {
        int o = swz128(((wc * 64 + nf * 16 + (lane & 15)) << 7) + kc * 64 + ((lane >> 4) << 4));
        bf[nf] = *reinterpret_cast<const bfx8*>(reinterpret_cast<const char*>(sB) + o);
      }
#pragma unroll
      for (int mf = 0; mf < 4; ++mf)
#pragma unroll
        for (int nf = 0; nf < 4; ++nf)
          acc[mf][nf] = __builtin_amdgcn_mfma_f32_16x16x32_bf16(af[mf], bf[nf], acc[mf][nf], 0, 0, 0);
    }
    __syncthreads();
  }
#pragma unroll
  for (int mf = 0; mf < 4; ++mf)
#pragma unroll
    for (int nf = 0; nf < 4; ++nf)
#pragma unroll
      for (int r = 0; r < 4; ++r) {
        const int row = bm + wr * 64 + mf * 16 + ((lane >> 4) << 2) + r;
        const int col = bn + wc * 64 + nf * 16 + (lane & 15);
        const float v = acc[mf][nf][r] + bias[col];
        const int chunk = col >> 10, w = col & 1023, h = w >> 6, dd = w & 63;
        const int b = row >> 11, s = row & 2047;
        const int bh = b * H_ + h;
        if (chunk == 0)
          outK[((size_t)bh * S_ + s) * D_ + dd] = f2bf(v);
        else if (chunk == 1)
          outQ[((size_t)bh * S_ + s) * D_ + dd] = f2bf(v);
        else
          outVt[((size_t)bh * D_ + dd) * S_ + s] = f2bf(v);  // fused V transpose
      }
}

// ---------------- proj GEMM (8 waves, 512 thr): fp32 out row-major ----------------
__global__ __launch_bounds__(512) void gemm_proj(const u16* __restrict__ A,
                                                 const u16* __restrict__ Bt,
                                                 const float* __restrict__ bias, int M, int N,
                                                 int K, float* __restrict__ outF) {
  __shared__ __align__(16) u16 sA[128 * 64];
  __shared__ __align__(16) u16 sB[128 * 64];
  const int tid = threadIdx.x, lane = tid & 63;
  const int wave = tid >> 6, wr = wave >> 2, wc = wave & 3;  // 2x4 waves of 64x32
  int lin = blockIdx.y * gridDim.x + blockIdx.x;
  const int nwg = gridDim.x * gridDim.y;
  if ((nwg & 7) == 0) {
    const int cpx = nwg >> 3;
    lin = (lin & 7) * cpx + (lin >> 3);
  }
  const int bm = (lin / gridDim.x) * 128, bn = (lin % gridDim.x) * 128;
  const int r8 = lane >> 3, c16 = (lane & 7) ^ r8;
  f32x4 acc[4][2] = {};
  for (int k0 = 0; k0 < K; k0 += 64) {
#pragma unroll
    for (int i = 0; i < 2; ++i) {
      const int c = wave * 2 + i;  // 16 chunks of 1KB
      const int row = c * 8 + r8;
      gload16(A + (size_t)(bm + row) * K + k0 + c16 * 8, (char*)sA + c * 1024);
      gload16(Bt + (size_t)(bn + row) * K + k0 + c16 * 8, (char*)sB + c * 1024);
    }
    __syncthreads();
#pragma unroll
    for (int kc = 0; kc < 2; ++kc) {
      bfx8 af[4], bf[2];
#pragma unroll
      for (int mf = 0; mf < 4; ++mf) {
        int o = swz128(((wr * 64 + mf * 16 + (lane & 15)) << 7) + kc * 64 + ((lane >> 4) << 4));
        af[mf] = *reinterpret_cast<const bfx8*>(reinterpret_cast<const char*>(sA) + o);
      }
#pragma unroll
      for (int nf = 0; nf < 2; ++nf) {
        int o = swz128(((wc * 32 + nf * 16 + (lane & 15)) << 7) + kc * 64 + ((lane >> 4) << 4));
        bf[nf] = *reinterpret_cast<const bfx8*>(reinterpret_cast<const char*>(sB) + o);
      }
#pragma unroll
      for (int mf = 0; mf < 4; ++mf)
#pragma unroll
        for (int nf = 0; nf < 2; ++nf)
          acc[mf][nf] = __builtin_amdgcn_mfma_f32_16x16x32_bf16(af[mf], bf[nf], acc[mf][nf], 0, 0, 0);
    }
    __syncthreads();
  }
#pragma unroll
  for (int mf = 0; mf < 4; ++mf)
#pragma unroll
    for (int nf = 0; nf < 2; ++nf)
#pragma unroll
      for (int r = 0; r < 4; ++r) {
        const int row = bm + wr * 64 + mf * 16 + ((lane >> 4) << 2) + r;
        const int col = bn + wc * 32 + nf * 16 + (lane & 15);
        outF[(size_t)row * N + col] = acc[mf][nf][r] + bias[col];
      }
}

// ---------------- flash attention with ALiBi, causal ----------------
// QBLK=64, KVBLK=64, 1024 blocks (4/CU). XCD-affine mapping: id&7 = XCD -> 4 bh per XCD,
// so each XCD's L2 holds its 4 heads' K+V (2 MB < 4 MB) and staging loads are L2 hits.
// Same-CU blocks (stride 256) still get qi {31-c, c, 31-c, c} -> uniform 66 tiles/CU.
// Swapped-operand 16x16 MFMA, exp2-domain softmax, l via ones-MFMA riding PV, defer-max.
__global__ __launch_bounds__(256, 4) void attn_alibi(const u16* __restrict__ Q,
                                                     const u16* __restrict__ Kb,
                                                     const u16* __restrict__ Vt,
                                                     const float* __restrict__ slopes,
                                                     u16* __restrict__ Y) {
  __shared__ __align__(16) u16 sK[2][4096];
  __shared__ __align__(16) u16 sV[2][4096];
  __shared__ __align__(16) __bf16 sP[4][16 * 64];
  const int id = blockIdx.x;
  const int xcd = id & 7, w = id >> 3;       // id%8 = XCD (round-robin dispatch)
  const int bh = xcd * 4 + (w >> 5);         // 4 heads pinned per XCD
  const int r5 = w & 31;
  const int qi = ((w >> 5) & 1) ? r5 : 31 - r5;  // same-CU balance preserved
  const int b = bh >> 4, h = bh & 15;
  const int tid = threadIdx.x, lane = tid & 63, wave = tid >> 6;
  const int q = lane & 15, g = lane >> 4;
  const int q0 = qi * 64;
  const int w0 = q0 + wave * 16;
  const float L2E = 1.44269504089f;
  const float SCALE = 0.125f * L2E;
  const float sl2 = slopes[h] * L2E;
  const size_t headSD = (size_t)bh * (S_ * D_);
  const size_t headDS = (size_t)bh * (D_ * S_);
  const int nt = qi + 1;
  const int r8 = lane >> 3, c16 = (lane & 7) ^ r8;

  bfx8 qf[2];
  {
    const u16* qp = Q + headSD + (size_t)(w0 + q) * D_ + g * 8;
    qf[0] = *reinterpret_cast<const bfx8*>(qp);
    qf[1] = *reinterpret_cast<const bfx8*>(qp + 32);
  }
  bfx8 onesf;
#pragma unroll
  for (int j = 0; j < 8; ++j) onesf[j] = (__bf16)1.0f;
  f32x4 base[4];
#pragma unroll
  for (int nf = 0; nf < 4; ++nf)
#pragma unroll
    for (int r = 0; r < 4; ++r) base[nf][r] = sl2 * (float)(nf * 16 + 4 * g + r);
  const int ir0 = wave * 16 + q;  // diagonal-tile mask boundary

  float m = 0.f;
  f32x4 oT[4] = {};
  f32x4 oX = {};  // l accumulator (all components equal l)

  auto stage = [&](int t, int buf) {
#pragma unroll
    for (int i = 0; i < 2; ++i) {
      const int c = wave * 2 + i;
      const int row = c * 8 + r8;
      gload16(Kb + headSD + (size_t)t * 4096 + row * 64 + c16 * 8, (char*)sK[buf] + c * 1024);
      gload16(Vt + headDS + (size_t)row * S_ + t * 64 + c16 * 8, (char*)sV[buf] + c * 1024);
    }
  };

  stage(0, 0);
  __syncthreads();
  int cur = 0;
  for (int t = 0; t < nt; ++t) {
    if (t + 1 < nt) stage(t + 1, cur ^ 1);
    const char* sKc = reinterpret_cast<const char*>(sK[cur]);
    const char* sVc = reinterpret_cast<const char*>(sV[cur]);
    f32x4 tt[4] = {};
    __builtin_amdgcn_s_setprio(1);
#pragma unroll
    for (int kc = 0; kc < 2; ++kc)
#pragma unroll
      for (int nf = 0; nf < 4; ++nf) {
        const bfx8 kf =
            *reinterpret_cast<const bfx8*>(sKc + swz128(((nf * 16 + q) << 7) + kc * 64 + (g << 4)));
        tt[nf] = __builtin_amdgcn_mfma_f32_16x16x32_bf16(kf, qf[kc], tt[nf], 0, 0, 0);
      }
    __builtin_amdgcn_s_setprio(0);
    const float tb = sl2 * (float)(t * 64);
    if (t != nt - 1) {
      // ---- non-diagonal tile: raw max + upper bound, fused bias+exp2 ----
      float rmax = -3.0e38f;
#pragma unroll
      for (int nf = 0; nf < 4; ++nf)
#pragma unroll
        for (int r = 0; r < 4; ++r) rmax = fmaxf(rmax, tt[nf][r]);
      rmax = fmaxf(rmax, __shfl_xor(rmax, 16));
      rmax = fmaxf(rmax, __shfl_xor(rmax, 32));
      const float bound = fmaf(rmax, SCALE, tb + sl2 * 63.f);  // >= true biased row max
      if (!__all(bound <= m + 12.0f)) {
        const float mnew = fmaxf(m, bound);
        const float corr = __builtin_amdgcn_exp2f(m - mnew);
        m = mnew;
#pragma unroll
        for (int nf = 0; nf < 4; ++nf) oT[nf] *= corr;
        oX *= corr;
      }
      const float tbm = tb - m;
#pragma unroll
      for (int nf = 0; nf < 4; ++nf) {
        const f32x4 bb = base[nf] + tbm;
#pragma unroll
        for (int r = 0; r < 4; ++r)
          tt[nf][r] = __builtin_amdgcn_exp2f(fmaf(tt[nf][r], SCALE, bb[r]));
      }
    } else {
      // ---- diagonal tile: exact per-element bias + causal mask ----
      float rmax = -3.0e38f;
#pragma unroll
      for (int nf = 0; nf < 4; ++nf)
#pragma unroll
        for (int r = 0; r < 4; ++r) {
          float sv = fmaf(tt[nf][r], SCALE, base[nf][r] + tb);
          if (nf * 16 + 4 * g + r > ir0) sv = -3.0e38f;
          tt[nf][r] = sv;
          rmax = fmaxf(rmax, sv);
        }
      rmax = fmaxf(rmax, __shfl_xor(rmax, 16));
      rmax = fmaxf(rmax, __shfl_xor(rmax, 32));
      if (!__all(rmax <= m + 12.0f)) {
        const float mnew = fmaxf(m, rmax);
        const float corr = __builtin_amdgcn_exp2f(m - mnew);
        m = mnew;
#pragma unroll
        for (int nf = 0; nf < 4; ++nf) oT[nf] *= corr;
        oX *= corr;
      }
#pragma unroll
      for (int nf = 0; nf < 4; ++nf)
#pragma unroll
        for (int r = 0; r < 4; ++r) tt[nf][r] = __builtin_amdgcn_exp2f(tt[nf][r] - m);
    }
    // P -> wave-private swizzled sP; wave-internal lgkm ordering, no barrier
    char* pw = reinterpret_cast<char*>(sP[wave]);
#pragma unroll
    for (int nf = 0; nf < 4; ++nf) {
      bfx4 w = {(__bf16)tt[nf][0], (__bf16)tt[nf][1], (__bf16)tt[nf][2], (__bf16)tt[nf][3]};
      *reinterpret_cast<bfx4*>(pw + swz128((q << 7) + nf * 32 + g * 8)) = w;
    }
    bfx8 pa[2];
#pragma unroll
    for (int kc = 0; kc < 2; ++kc)
      pa[kc] = *reinterpret_cast<const bfx8*>(pw + swz128((q << 7) + kc * 64 + (g << 4)));
    __builtin_amdgcn_s_setprio(1);
#pragma unroll
    for (int kc = 0; kc < 2; ++kc) {
#pragma unroll
      for (int nf = 0; nf < 4; ++nf) {
        const bfx8 vf =
            *reinterpret_cast<const bfx8*>(sVc + swz128(((nf * 16 + q) << 7) + kc * 64 + (g << 4)));
        oT[nf] = __builtin_amdgcn_mfma_f32_16x16x32_bf16(vf, pa[kc], oT[nf], 0, 0, 0);
      }
      oX = __builtin_amdgcn_mfma_f32_16x16x32_bf16(onesf, pa[kc], oX, 0, 0, 0);  // l rides PV
    }
    __builtin_amdgcn_s_setprio(0);
    __syncthreads();
    cur ^= 1;
  }
  const float rl = 1.0f / oX[0];
  const int row = w0 + q;
#pragma unroll
  for (int nf = 0; nf < 4; ++nf) {
    bfx4 w = {(__bf16)(oT[nf][0] * rl), (__bf16)(oT[nf][1] * rl), (__bf16)(oT[nf][2] * rl),
              (__bf16)(oT[nf][3] * rl)};
    const int col = h * 64 + nf * 16 + g * 4;
    *reinterpret_cast<bfx4*>(reinterpret_cast<char*>(Y) + (((size_t)b * S_ + row) * E_ + col) * 2) =
        w;
  }
}

extern "C" void kernel_launch(void* const* d_in, const int* in_sizes, int n_in, void* d_out,
                              int out_size, void* d_ws, size_t ws_size, hipStream_t stream) {
  (void)in_sizes; (void)n_in; (void)out_size; (void)ws_size;
  const float* x = (const float*)d_in[0];
  const float* Wkqv = (const float*)d_in[1];
  const float* bkqv = (const float*)d_in[2];
  const float* Wproj = (const float*)d_in[3];
  const float* bproj = (const float*)d_in[4];
  const float* slopes = (const float*)d_in[5];
  float* out = (float*)d_out;

  const size_t MBE = (size_t)4096 * 1024;
  u16* xb = (u16*)d_ws;                       // x bf16              [4096][1024]
  u16* wkqvt = xb + MBE;                      // W_kqv^T bf16        [3072][1024]
  u16* wprojt = wkqvt + (size_t)3072 * 1024;  // W_proj^T bf16       [1024][1024]
  u16* kbuf = wprojt + (size_t)1024 * 1024;   // K   [B][H][S][D]
  u16* qbuf = kbuf + MBE;                     // Q   [B][H][S][D]
  u16* vtbuf = qbuf + MBE;                    // V^T [B][H][D][S]
  u16* ybuf = vtbuf + MBE;                    // attn out [B][S][E]

  prep<<<dim3(3072), dim3(256), 0, stream>>>(x, Wkqv, Wproj, xb, wkqvt, wprojt);
  gemm_kqv<<<dim3(24, 32), dim3(256), 0, stream>>>(xb, wkqvt, bkqv, 4096, 3072, 1024, kbuf, qbuf,
                                                   vtbuf);
  attn_alibi<<<dim3(1024), dim3(256), 0, stream>>>(qbuf, kbuf, vtbuf, slopes, ybuf);
  gemm_proj<<<dim3(8, 32), dim3(512), 0, stream>>>(ybuf, wprojt, bproj, 4096, 1024, 1024, out);
}

// Round 9
// 115.043 us; speedup vs baseline: 1.3886x; 1.0283x over previous
//
#include <hip/hip_runtime.h>

typedef unsigned short u16;
typedef float f32x4 __attribute__((ext_vector_type(4)));
typedef __bf16 bfx8 __attribute__((ext_vector_type(8)));
typedef __bf16 bfx4 __attribute__((ext_vector_type(4)));
typedef u16 u16x8 __attribute__((ext_vector_type(8)));
typedef u16 u16x4 __attribute__((ext_vector_type(4)));

#define B_ 2
#define S_ 2048
#define E_ 1024
#define H_ 16
#define D_ 64

__device__ __forceinline__ u16 f2bf(float f) {
  unsigned u = __float_as_uint(f);
  u = u + 0x7FFFu + ((u >> 16) & 1u);  // RNE
  return (u16)(u >> 16);
}

// XOR swizzle for tiles with 128B rows: byte ^= ((row&7)<<4).
__device__ __forceinline__ int swz128(int o) { return o ^ ((o >> 3) & 0x70); }

// async global->LDS, 16B per lane; LDS dest is wave-uniform base (HW adds lane*16).
__device__ __forceinline__ void gload16(const void* g, void* l) {
  __builtin_amdgcn_global_load_lds((const __attribute__((address_space(1))) void*)g,
                                   (__attribute__((address_space(3))) void*)l, 16, 0, 0);
}

// Chunk table: 60 work items per (bh): (qi, t0, t1, slot), ordered ~longest-first.
// slot >= 0 -> partial chunk (needs merge); slot < 0 -> sole chunk, writes Y directly.
__device__ const signed char TQI[60] = {31, 31, 30, 30, 29, 29, 28, 28, 27, 27, 26, 26, 25, 25, 24,
                                        24, 23, 23, 22, 21, 20, 19, 18, 17, 16, 15, 14, 13, 12, 11,
                                        22, 10, 21, 9,  20, 8,  31, 19, 7,  30, 18, 6,  29, 17, 5,
                                        28, 16, 4,  27, 15, 3,  26, 14, 2,  25, 13, 1,  24, 12, 0};
__device__ const signed char TT0[60] = {0,  12, 0,  12, 0,  12, 0,  12, 0,  12, 0,  12, 0,  12, 0,
                                        12, 0,  12, 0,  0,  0,  0,  0,  0,  0,  0,  0,  0,  0,  0,
                                        12, 0,  12, 0,  12, 0,  24, 12, 0,  24, 12, 0,  24, 12, 0,
                                        24, 12, 0,  24, 12, 0,  24, 12, 0,  24, 12, 0,  24, 12, 0};
__device__ const signed char TT1[60] = {12, 24, 12, 24, 12, 24, 12, 24, 12, 24, 12, 24, 12, 24, 12,
                                        24, 12, 24, 12, 12, 12, 12, 12, 12, 12, 12, 12, 12, 12, 12,
                                        23, 11, 22, 10, 21, 9,  32, 20, 8,  31, 19, 7,  30, 18, 6,
                                        29, 17, 5,  28, 16, 4,  27, 15, 3,  26, 14, 2,  25, 13, 1};
__device__ const signed char TSL[60] = {45, 46, 42, 43, 39, 40, 36, 37, 33, 34, 30, 31, 27, 28, 24,
                                        25, 22, 23, 20, 18, 16, 14, 12, 10, 8,  6,  4,  2,  0,  -1,
                                        21, -1, 19, -1, 17, -1, 47, 15, -1, 44, 13, -1, 41, 11, -1,
                                        38, 9,  -1, 35, 7,  -1, 32, 5,  -1, 29, 3,  -1, 26, 1,  -1};

// ---------------- fused prep: x->bf16 convert + W_kqv^T + W_proj^T (bf16) ----------------
__global__ __launch_bounds__(256) void prep(const float* __restrict__ x,
                                            const float* __restrict__ Wk,
                                            const float* __restrict__ Wp, u16* __restrict__ xb,
                                            u16* __restrict__ wkt, u16* __restrict__ wpt) {
  __shared__ float tile[64][65];
  const int id = blockIdx.x, tid = threadIdx.x;
  if (id < 2048) {  // convert x: 2^20 float4 elements
    const float4* in4 = reinterpret_cast<const float4*>(x);
    u16x4* out4 = reinterpret_cast<u16x4*>(xb);
    int i = id * 256 + tid;
#pragma unroll
    for (int p = 0; p < 2; ++p, i += 524288) {
      const float4 v = in4[i];
      u16x4 o = {f2bf(v.x), f2bf(v.y), f2bf(v.z), f2bf(v.w)};
      out4[i] = o;
    }
    return;
  }
  const float* in;
  u16* out;
  int R, C, bx, by;
  if (id < 2816) {
    const int t = id - 2048;
    in = Wk; out = wkt; R = 1024; C = 3072; bx = t % 48; by = t / 48;
  } else {
    const int t = id - 2816;
    in = Wp; out = wpt; R = 1024; C = 1024; bx = t & 15; by = t >> 4;
  }
  const int ct = bx * 64, rt = by * 64;
#pragma unroll
  for (int p = 0; p < 4; ++p) {
    int f = p * 256 + tid;
    int row = f >> 4, c4 = (f & 15) << 2;
    const float4 v = *reinterpret_cast<const float4*>(in + (size_t)(rt + row) * C + ct + c4);
    tile[row][c4 + 0] = v.x; tile[row][c4 + 1] = v.y;
    tile[row][c4 + 2] = v.z; tile[row][c4 + 3] = v.w;
  }
  __syncthreads();
#pragma unroll
  for (int p = 0; p < 4; ++p) {
    int g = p * 256 + tid;
    int orow = g >> 4, k4 = (g & 15) << 2;
    u16x4 o = {f2bf(tile[k4 + 0][orow]), f2bf(tile[k4 + 1][orow]),
               f2bf(tile[k4 + 2][orow]), f2bf(tile[k4 + 3][orow])};
    *reinterpret_cast<u16x4*>(out + (size_t)(ct + orow) * R + rt + k4) = o;
  }
}

// ---------------- bf16 GEMM (4 waves): C = A @ Bt^T + bias; EPI0 scatters K/Q/V^T ----------------
__global__ __launch_bounds__(256) void gemm_kqv(const u16* __restrict__ A,
                                                const u16* __restrict__ Bt,
                                                const float* __restrict__ bias, int M, int N, int K,
                                                u16* __restrict__ outK, u16* __restrict__ outQ,
                                                u16* __restrict__ outVt) {
  __shared__ __align__(16) u16 sA[128 * 64];
  __shared__ __align__(16) u16 sB[128 * 64];
  const int tid = threadIdx.x, lane = tid & 63;
  const int wave = tid >> 6, wr = wave >> 1, wc = wave & 1;
  int lin = blockIdx.y * gridDim.x + blockIdx.x;
  const int nwg = gridDim.x * gridDim.y;
  if ((nwg & 7) == 0) {  // bijective XCD-chunked swizzle
    const int cpx = nwg >> 3;
    lin = (lin & 7) * cpx + (lin >> 3);
  }
  const int bm = (lin / gridDim.x) * 128, bn = (lin % gridDim.x) * 128;
  const int r8 = lane >> 3, c16 = (lane & 7) ^ r8;
  f32x4 acc[4][4] = {};
  for (int k0 = 0; k0 < K; k0 += 64) {
#pragma unroll
    for (int i = 0; i < 4; ++i) {
      const int c = wave * 4 + i;
      const int row = c * 8 + r8;
      gload16(A + (size_t)(bm + row) * K + k0 + c16 * 8, (char*)sA + c * 1024);
      gload16(Bt + (size_t)(bn + row) * K + k0 + c16 * 8, (char*)sB + c * 1024);
    }
    __syncthreads();
#pragma unroll
    for (int kc = 0; kc < 2; ++kc) {
      bfx8 af[4], bf[4];
#pragma unroll
      for (int mf = 0; mf < 4; ++mf) {
        int o = swz128(((wr * 64 + mf * 16 + (lane & 15)) << 7) + kc * 64 + ((lane >> 4) << 4));
        af[mf] = *reinterpret_cast<const bfx8*>(reinterpret_cast<const char*>(sA) + o);
      }
#pragma unroll
      for (int nf = 0; nf < 4; ++nf) {
        int o = swz128(((wc * 64 + nf * 16 + (lane & 15)) << 7) + kc * 64 + ((lane >> 4) << 4));
        bf[nf] = *reinterpret_cast<const bfx8*>(reinterpret_cast<const char*>(sB) + o);
      }
#pragma unroll
      for (int mf = 0; mf < 4; ++mf)
#pragma unroll
        for (int nf = 0; nf < 4; ++nf)
          acc[mf][nf] = __builtin_amdgcn_mfma_f32_16x16x32_bf16(af[mf], bf[nf], acc[mf][nf], 0, 0, 0);
    }
    __syncthreads();
  }
#pragma unroll
  for (int mf = 0; mf < 4; ++mf)
#pragma unroll
    for (int nf = 0; nf < 4; ++nf)
#pragma unroll
      for (int r = 0; r < 4; ++r) {
        const int row = bm + wr * 64 + mf * 16 + ((lane >> 4) << 2) + r;
        const int col = bn + wc * 64 + nf * 16 + (lane & 15);
        const float v = acc[mf][nf][r] + bias[col];
        const int chunk = col >> 10, w = col & 1023, h = w >> 6, dd = w & 63;
        const int b = row >> 11, s = row & 2047;
        const int bh = b * H_ + h;
        if (chunk == 0)
          outK[((size_t)bh * S_ + s) * D_ + dd] = f2bf(v);
        else if (chunk == 1)
          outQ[((size_t)bh * S_ + s) * D_ + dd] = f2bf(v);
        else
          outVt[((size_t)bh * D_ + dd) * S_ + s] = f2bf(v);  // fused V transpose
      }
}

// ---------------- proj GEMM (8 waves, 512 thr): fp32 out row-major ----------------
__global__ __launch_bounds__(512) void gemm_proj(const u16* __restrict__ A,
                                                 const u16* __restrict__ Bt,
                                                 const float* __restrict__ bias, int M, int N,
                                                 int K, float* __restrict__ outF) {
  __shared__ __align__(16) u16 sA[128 * 64];
  __shared__ __align__(16) u16 sB[128 * 64];
  const int tid = threadIdx.x, lane = tid & 63;
  const int wave = tid >> 6, wr = wave >> 2, wc = wave & 3;  // 2x4 waves of 64x32
  int lin = blockIdx.y * gridDim.x + blockIdx.x;
  const int nwg = gridDim.x * gridDim.y;
  if ((nwg & 7) == 0) {
    const int cpx = nwg >> 3;
    lin = (lin & 7) * cpx + (lin >> 3);
  }
  const int bm = (lin / gridDim.x) * 128, bn = (lin % gridDim.x) * 128;
  const int r8 = lane >> 3, c16 = (lane & 7) ^ r8;
  f32x4 acc[4][2] = {};
  for (int k0 = 0; k0 < K; k0 += 64) {
#pragma unroll
    for (int i = 0; i < 2; ++i) {
      const int c = wave * 2 + i;  // 16 chunks of 1KB
      const int row = c * 8 + r8;
      gload16(A + (size_t)(bm + row) * K + k0 + c16 * 8, (char*)sA + c * 1024);
      gload16(Bt + (size_t)(bn + row) * K + k0 + c16 * 8, (char*)sB + c * 1024);
    }
    __syncthreads();
#pragma unroll
    for (int kc = 0; kc < 2; ++kc) {
      bfx8 af[4], bf[2];
#pragma unroll
      for (int mf = 0; mf < 4; ++mf) {
        int o = swz128(((wr * 64 + mf * 16 + (lane & 15)) << 7) + kc * 64 + ((lane >> 4) << 4));
        af[mf] = *reinterpret_cast<const bfx8*>(reinterpret_cast<const char*>(sA) + o);
      }
#pragma unroll
      for (int nf = 0; nf < 2; ++nf) {
        int o = swz128(((wc * 32 + nf * 16 + (lane & 15)) << 7) + kc * 64 + ((lane >> 4) << 4));
        bf[nf] = *reinterpret_cast<const bfx8*>(reinterpret_cast<const char*>(sB) + o);
      }
#pragma unroll
      for (int mf = 0; mf < 4; ++mf)
#pragma unroll
        for (int nf = 0; nf < 2; ++nf)
          acc[mf][nf] = __builtin_amdgcn_mfma_f32_16x16x32_bf16(af[mf], bf[nf], acc[mf][nf], 0, 0, 0);
    }
    __syncthreads();
  }
#pragma unroll
  for (int mf = 0; mf < 4; ++mf)
#pragma unroll
    for (int nf = 0; nf < 2; ++nf)
#pragma unroll
      for (int r = 0; r < 4; ++r) {
        const int row = bm + wr * 64 + mf * 16 + ((lane >> 4) << 2) + r;
        const int col = bn + wc * 32 + nf * 16 + (lane & 15);
        outF[(size_t)row * N + col] = acc[mf][nf][r] + bias[col];
      }
}

// ---------------- flash attention with ALiBi, causal — split-KV chunked ----------------
// 1920 blocks = 8 XCD x 4 bh x 60 chunks. Chunk = (qi, [t0,t1)) of <=12 KV tiles; 4 blocks/CU
// resident constantly (LDS 40KB), excess queue smooths the triangular imbalance.
// Per-tile math identical to the verified R8 kernel. Sole chunks write Y directly; split
// chunks write unnormalized O (bf16) + per-row (m,l) partials, combined by merge_attn.
__global__ __launch_bounds__(256, 4) void attn_alibi(const u16* __restrict__ Q,
                                                     const u16* __restrict__ Kb,
                                                     const u16* __restrict__ Vt,
                                                     const float* __restrict__ slopes,
                                                     u16* __restrict__ Y, u16* __restrict__ pO,
                                                     float* __restrict__ pML) {
  __shared__ __align__(16) u16 sK[2][4096];
  __shared__ __align__(16) u16 sV[2][4096];
  __shared__ __align__(16) __bf16 sP[4][16 * 64];
  const int id = blockIdx.x;
  const int xcd = id & 7, j = id >> 3;       // id%8 = XCD (round-robin dispatch)
  const int bh = xcd * 4 + (j & 3);          // 4 heads pinned per XCD (L2-resident K/V)
  const int c = j >> 2;                      // 0..59 chunk-table index (wave-uniform s_load)
  const int qi = TQI[c], t0 = TT0[c], t1 = TT1[c], slot = TSL[c];
  const int b = bh >> 4, h = bh & 15;
  const int tid = threadIdx.x, lane = tid & 63, wave = tid >> 6;
  const int q = lane & 15, g = lane >> 4;
  const int q0 = qi * 64;
  const int w0 = q0 + wave * 16;
  const float L2E = 1.44269504089f;
  const float SCALE = 0.125f * L2E;
  const float sl2 = slopes[h] * L2E;
  const size_t headSD = (size_t)bh * (S_ * D_);
  const size_t headDS = (size_t)bh * (D_ * S_);
  const int r8 = lane >> 3, c16 = (lane & 7) ^ r8;

  bfx8 qf[2];
  {
    const u16* qp = Q + headSD + (size_t)(w0 + q) * D_ + g * 8;
    qf[0] = *reinterpret_cast<const bfx8*>(qp);
    qf[1] = *reinterpret_cast<const bfx8*>(qp + 32);
  }
  bfx8 onesf;
#pragma unroll
  for (int jj = 0; jj < 8; ++jj) onesf[jj] = (__bf16)1.0f;
  f32x4 base[4];
#pragma unroll
  for (int nf = 0; nf < 4; ++nf)
#pragma unroll
    for (int r = 0; r < 4; ++r) base[nf][r] = sl2 * (float)(nf * 16 + 4 * g + r);
  const int ir0 = wave * 16 + q;  // diagonal-tile mask boundary

  float m = 0.f;
  f32x4 oT[4] = {};
  f32x4 oX = {};  // l accumulator (all components equal l)

  auto stage = [&](int t, int buf) {
#pragma unroll
    for (int i = 0; i < 2; ++i) {
      const int cc = wave * 2 + i;
      const int row = cc * 8 + r8;
      gload16(Kb + headSD + (size_t)t * 4096 + row * 64 + c16 * 8, (char*)sK[buf] + cc * 1024);
      gload16(Vt + headDS + (size_t)row * S_ + t * 64 + c16 * 8, (char*)sV[buf] + cc * 1024);
    }
  };

  stage(t0, 0);
  __syncthreads();
  int cur = 0;
  for (int t = t0; t < t1; ++t) {
    if (t + 1 < t1) stage(t + 1, cur ^ 1);
    const char* sKc = reinterpret_cast<const char*>(sK[cur]);
    const char* sVc = reinterpret_cast<const char*>(sV[cur]);
    f32x4 tt[4] = {};
    __builtin_amdgcn_s_setprio(1);
#pragma unroll
    for (int kc = 0; kc < 2; ++kc)
#pragma unroll
      for (int nf = 0; nf < 4; ++nf) {
        const bfx8 kf =
            *reinterpret_cast<const bfx8*>(sKc + swz128(((nf * 16 + q) << 7) + kc * 64 + (g << 4)));
        tt[nf] = __builtin_amdgcn_mfma_f32_16x16x32_bf16(kf, qf[kc], tt[nf], 0, 0, 0);
      }
    __builtin_amdgcn_s_setprio(0);
    const float tb = sl2 * (float)(t * 64);
    if (t != qi) {
      // ---- non-diagonal tile: raw max + upper bound, fused bias+exp2 ----
      float rmax = -3.0e38f;
#pragma unroll
      for (int nf = 0; nf < 4; ++nf)
#pragma unroll
        for (int r = 0; r < 4; ++r) rmax = fmaxf(rmax, tt[nf][r]);
      rmax = fmaxf(rmax, __shfl_xor(rmax, 16));
      rmax = fmaxf(rmax, __shfl_xor(rmax, 32));
      const float bound = fmaf(rmax, SCALE, tb + sl2 * 63.f);  // >= true biased row max
      if (!__all(bound <= m + 12.0f)) {
        const float mnew = fmaxf(m, bound);
        const float corr = __builtin_amdgcn_exp2f(m - mnew);
        m = mnew;
#pragma unroll
        for (int nf = 0; nf < 4; ++nf) oT[nf] *= corr;
        oX *= corr;
      }
      const float tbm = tb - m;
#pragma unroll
      for (int nf = 0; nf < 4; ++nf) {
        const f32x4 bb = base[nf] + tbm;
#pragma unroll
        for (int r = 0; r < 4; ++r)
          tt[nf][r] = __builtin_amdgcn_exp2f(fmaf(tt[nf][r], SCALE, bb[r]));
      }
    } else {
      // ---- diagonal tile: exact per-element bias + causal mask ----
      float rmax = -3.0e38f;
#pragma unroll
      for (int nf = 0; nf < 4; ++nf)
#pragma unroll
        for (int r = 0; r < 4; ++r) {
          float sv = fmaf(tt[nf][r], SCALE, base[nf][r] + tb);
          if (nf * 16 + 4 * g + r > ir0) sv = -3.0e38f;
          tt[nf][r] = sv;
          rmax = fmaxf(rmax, sv);
        }
      rmax = fmaxf(rmax, __shfl_xor(rmax, 16));
      rmax = fmaxf(rmax, __shfl_xor(rmax, 32));
      if (!__all(rmax <= m + 12.0f)) {
        const float mnew = fmaxf(m, rmax);
        const float corr = __builtin_amdgcn_exp2f(m - mnew);
        m = mnew;
#pragma unroll
        for (int nf = 0; nf < 4; ++nf) oT[nf] *= corr;
        oX *= corr;
      }
#pragma unroll
      for (int nf = 0; nf < 4; ++nf)
#pragma unroll
        for (int r = 0; r < 4; ++r) tt[nf][r] = __builtin_amdgcn_exp2f(tt[nf][r] - m);
    }
    // P -> wave-private swizzled sP; wave-internal lgkm ordering, no barrier
    char* pw = reinterpret_cast<char*>(sP[wave]);
#pragma unroll
    for (int nf = 0; nf < 4; ++nf) {
      bfx4 w = {(__bf16)tt[nf][0], (__bf16)tt[nf][1], (__bf16)tt[nf][2], (__bf16)tt[nf][3]};
      *reinterpret_cast<bfx4*>(pw + swz128((q << 7) + nf * 32 + g * 8)) = w;
    }
    bfx8 pa[2];
#pragma unroll
    for (int kc = 0; kc < 2; ++kc)
      pa[kc] = *reinterpret_cast<const bfx8*>(pw + swz128((q << 7) + kc * 64 + (g << 4)));
    __builtin_amdgcn_s_setprio(1);
#pragma unroll
    for (int kc = 0; kc < 2; ++kc) {
#pragma unroll
      for (int nf = 0; nf < 4; ++nf) {
        const bfx8 vf =
            *reinterpret_cast<const bfx8*>(sVc + swz128(((nf * 16 + q) << 7) + kc * 64 + (g << 4)));
        oT[nf] = __builtin_amdgcn_mfma_f32_16x16x32_bf16(vf, pa[kc], oT[nf], 0, 0, 0);
      }
      oX = __builtin_amdgcn_mfma_f32_16x16x32_bf16(onesf, pa[kc], oX, 0, 0, 0);  // l rides PV
    }
    __builtin_amdgcn_s_setprio(0);
    __syncthreads();
    cur ^= 1;
  }
  if (slot < 0) {
    // sole chunk: normalize and write Y directly
    const float rl = 1.0f / oX[0];
    const int row = w0 + q;
#pragma unroll
    for (int nf = 0; nf < 4; ++nf) {
      bfx4 w = {(__bf16)(oT[nf][0] * rl), (__bf16)(oT[nf][1] * rl), (__bf16)(oT[nf][2] * rl),
                (__bf16)(oT[nf][3] * rl)};
      const int col = h * 64 + nf * 16 + g * 4;
      *reinterpret_cast<bfx4*>(reinterpret_cast<char*>(Y) +
                               (((size_t)b * S_ + row) * E_ + col) * 2) = w;
    }
  } else {
    // partial chunk: write raw O (bf16) + (m, l) per row
    const int sg = bh * 48 + slot;
    u16* po = pO + (size_t)sg * 4096 + (size_t)(wave * 16 + q) * 64;
#pragma unroll
    for (int nf = 0; nf < 4; ++nf) {
      bfx4 w = {(__bf16)oT[nf][0], (__bf16)oT[nf][1], (__bf16)oT[nf][2], (__bf16)oT[nf][3]};
      *reinterpret_cast<bfx4*>(po + nf * 16 + g * 4) = w;
    }
    if (g == 0) {
      float2 ml = make_float2(m, oX[0]);
      reinterpret_cast<float2*>(pML)[sg * 64 + wave * 16 + q] = ml;
    }
  }
}

// ---------------- merge partial chunks: Y[rows] = sum_c w_c O_c / sum_c w_c l_c ----------------
__global__ __launch_bounds__(256) void merge_attn(const u16* __restrict__ pO,
                                                  const float* __restrict__ pML,
                                                  u16* __restrict__ Y) {
  const int mb = blockIdx.x;
  const int bh = mb / 20, qq = mb % 20, qi = 12 + qq;  // only qi>=12 are split
  const int nch = (qi < 24) ? 2 : 3;
  const int sb = (qi < 24) ? (qi - 12) * 2 : 24 + (qi - 24) * 3;
  const int b = bh >> 4, h = bh & 15;
  const int tid = threadIdx.x;
  const int r = tid >> 2, dq = (tid & 3) * 16;
  const float2* ml2 = reinterpret_cast<const float2*>(pML);
  float mm[3], ll[3];
  float M = -3.0e38f;
#pragma unroll
  for (int c = 0; c < 3; ++c) {
    if (c < nch) {
      const float2 v = ml2[(bh * 48 + sb + c) * 64 + r];
      mm[c] = v.x;
      ll[c] = v.y;
      M = fmaxf(M, v.x);
    } else {
      mm[c] = -3.0e38f;
      ll[c] = 0.f;
    }
  }
  float L = 0.f, acc[16];
#pragma unroll
  for (int i = 0; i < 16; ++i) acc[i] = 0.f;
#pragma unroll
  for (int c = 0; c < 3; ++c) {
    if (c < nch) {
      const float w = __builtin_amdgcn_exp2f(mm[c] - M);
      L += w * ll[c];
      const u16* src = pO + (size_t)(bh * 48 + sb + c) * 4096 + r * 64 + dq;
      const u16x8 a = *reinterpret_cast<const u16x8*>(src);
      const u16x8 bb = *reinterpret_cast<const u16x8*>(src + 8);
#pragma unroll
      for (int i = 0; i < 8; ++i) {
        acc[i] += w * __uint_as_float(((unsigned)a[i]) << 16);
        acc[8 + i] += w * __uint_as_float(((unsigned)bb[i]) << 16);
      }
    }
  }
  const float rl = 1.0f / L;
  u16x8 o0, o1;
#pragma unroll
  for (int i = 0; i < 8; ++i) {
    o0[i] = f2bf(acc[i] * rl);
    o1[i] = f2bf(acc[8 + i] * rl);
  }
  u16* dst = Y + ((size_t)b * S_ + qi * 64 + r) * E_ + h * 64 + dq;
  *reinterpret_cast<u16x8*>(dst) = o0;
  *reinterpret_cast<u16x8*>(dst + 8) = o1;
}

extern "C" void kernel_launch(void* const* d_in, const int* in_sizes, int n_in, void* d_out,
                              int out_size, void* d_ws, size_t ws_size, hipStream_t stream) {
  (void)in_sizes; (void)n_in; (void)out_size; (void)ws_size;
  const float* x = (const float*)d_in[0];
  const float* Wkqv = (const float*)d_in[1];
  const float* bkqv = (const float*)d_in[2];
  const float* Wproj = (const float*)d_in[3];
  const float* bproj = (const float*)d_in[4];
  const float* slopes = (const float*)d_in[5];
  float* out = (float*)d_out;

  const size_t MBE = (size_t)4096 * 1024;
  u16* xb = (u16*)d_ws;                       // x bf16              [4096][1024]
  u16* wkqvt = xb + MBE;                      // W_kqv^T bf16        [3072][1024]
  u16* wprojt = wkqvt + (size_t)3072 * 1024;  // W_proj^T bf16       [1024][1024]
  u16* kbuf = wprojt + (size_t)1024 * 1024;   // K   [B][H][S][D]
  u16* qbuf = kbuf + MBE;                     // Q   [B][H][S][D]
  u16* vtbuf = qbuf + MBE;                    // V^T [B][H][D][S]
  u16* ybuf = vtbuf + MBE;                    // attn out [B][S][E]
  // partial-chunk scratch overlays xb+wkqvt (dead after gemm_kqv): 12.6 MB O + 0.79 MB ml
  u16* pO = xb;                                      // [1536][64][64] bf16
  float* pML = (float*)(xb + (size_t)1536 * 4096);   // [1536][64][2] f32

  prep<<<dim3(3072), dim3(256), 0, stream>>>(x, Wkqv, Wproj, xb, wkqvt, wprojt);
  gemm_kqv<<<dim3(24, 32), dim3(256), 0, stream>>>(xb, wkqvt, bkqv, 4096, 3072, 1024, kbuf, qbuf,
                                                   vtbuf);
  attn_alibi<<<dim3(1920), dim3(256), 0, stream>>>(qbuf, kbuf, vtbuf, slopes, ybuf, pO, pML);
  merge_attn<<<dim3(640), dim3(256), 0, stream>>>(pO, pML, ybuf);
  gemm_proj<<<dim3(8, 32), dim3(512), 0, stream>>>(ybuf, wprojt, bproj, 4096, 1024, 1024, out);
}